// Round 7
// baseline (471.936 us; speedup 1.0000x reference)
//
#include <hip/hip_runtime.h>

#define N_NODES 100000
#define N_EDGES 1600000
#define HD 128
#define SLOPE 0.2f
#define GB 782              // gemm tiles: ceil(N_NODES/128)
#define CAP 32              // adjacency bucket capacity (P(deg>32) ~ 1e-19)
#define NN64 100352         // wave-aligned (x64) cover of N_NODES
#define NBK 512             // persistent blocks: 2/CU x 256 CU, co-residency
                            // guaranteed by __launch_bounds__(512,4) (<=128 VGPR)

typedef __attribute__((ext_vector_type(8))) short bf16x8;
typedef __attribute__((ext_vector_type(4))) float f32x4;

__device__ __forceinline__ unsigned short f2bf(float f) {
    union { float f; unsigned u; } v; v.f = f;
    const unsigned u = v.u + 0x7FFFu + ((v.u >> 16) & 1u);   // RNE
    return (unsigned short)(u >> 16);
}
__device__ __forceinline__ unsigned pack2(float lo, float hi) {
    return (unsigned)f2bf(lo) | ((unsigned)f2bf(hi) << 16);
}
__device__ __forceinline__ float bf2f(unsigned u16) {
    union { unsigned u; float f; } v; v.u = u16 << 16; return v.f;
}

// Hand-rolled grid barrier: monotonic counter, epoch target = NBK*epoch.
// Release on arrive (orders my prior writes), acquire on spin-exit (orders my
// subsequent reads). Device (agent) scope -> cross-XCD safe. All NBK blocks
// are co-resident by construction, so progress is guaranteed.
__device__ __forceinline__ void gbar(int* bar, int target) {
    __syncthreads();
    if (threadIdx.x == 0) {
        __hip_atomic_fetch_add(bar, 1, __ATOMIC_ACQ_REL, __HIP_MEMORY_SCOPE_AGENT);
        while (__hip_atomic_load(bar, __ATOMIC_ACQUIRE, __HIP_MEMORY_SCOPE_AGENT) < target) {}
    }
    __syncthreads();
}

// ---------------------------------------------------------------------------
// Mega-kernel, regular launch, hand-rolled barriers. 5 phases:
// P0 init -> bar -> P1 edge-bucket + P2 gemm (independent, no bar between)
// -> bar -> P3 gather -> bar -> P4 final. Phase bodies identical to the
// round-5 kernels (known-correct at 178us as 5 dispatches).
// ---------------------------------------------------------------------------
__global__ __launch_bounds__(512, 4) void k_mega(
    const int* __restrict__ h,
    const int* __restrict__ ei,
    const int* __restrict__ nt,
    const float* __restrict__ emb,
    const float* __restrict__ W1,
    const float* __restrict__ a_src1,
    const float* __restrict__ a_dst1,
    const float* __restrict__ b1,
    const float* __restrict__ W2,
    const float* __restrict__ a_src2,
    const float* __restrict__ a_dst2,
    const float* __restrict__ b2,
    float* __restrict__ out,
    unsigned short* __restrict__ xp1,
    float* __restrict__ es1,
    float* __restrict__ ed1,
    float* __restrict__ denom1,
    float* __restrict__ xp2,
    int* __restrict__ deg,
    unsigned* __restrict__ umask,
    unsigned short* __restrict__ W1bfT,
    int* __restrict__ adj,
    int* __restrict__ bar)
{
    __shared__ unsigned short Wlds[HD * HD];   // 32 KB
    const int tid  = threadIdx.x;
    const int gt   = (int)blockIdx.x * 512 + tid;
    const int gstr = NBK * 512;                // 262144
    const int w    = tid >> 6;
    const int lane = tid & 63;
    const int lm   = lane & 15;
    const int lg   = lane >> 4;

    // ---------------- P0: zero deg + active bitmask + W1^T bf16 ----------
    if (gt < NN64) {                            // single pass: gstr > NN64
        bool act = false;
        if (gt < N_NODES) { deg[gt] = 0; act = (nt[gt] == 0); }
        const unsigned long long bal = __ballot(act);
        if (lane == 0)       umask[gt >> 5] = (unsigned)bal;
        else if (lane == 32) umask[gt >> 5] = (unsigned)(bal >> 32);
    }
    if (gt < HD * HD) {
        const int n = gt >> 7, k = gt & 127;
        W1bfT[n * HD + k] = f2bf(W1[k * HD + n]);
    }
    gbar(bar, NBK * 1);

    // ---------------- P1: edge bucket-build (2 edges/thread) -------------
    for (int t2 = gt; t2 < (N_EDGES >> 1); t2 += gstr) {
        const int e0 = t2 << 1;
        const int2 s2 = *(const int2*)(ei + e0);
        const int2 d2 = *(const int2*)(ei + N_EDGES + e0);
        const bool a0 =
            (((umask[s2.x >> 5] >> (s2.x & 31)) & (umask[d2.x >> 5] >> (d2.x & 31))) & 1u) != 0u;
        const bool a1 =
            (((umask[s2.y >> 5] >> (s2.y & 31)) & (umask[d2.y >> 5] >> (d2.y & 31))) & 1u) != 0u;
        if (a0) {
            const int sl = atomicAdd(deg + d2.x, 1);
            if (sl < CAP) adj[(size_t)d2.x * CAP + sl] = s2.x;
        }
        if (a1) {
            const int sl = atomicAdd(deg + d2.y, 1);
            if (sl < CAP) adj[(size_t)d2.y * CAP + sl] = s2.y;
        }
    }

    // ---------------- P2: gemm1 (independent of P1 — no barrier) ---------
    // stage W^T once per block: thread t -> col n = t>>2, quarter (t&3)*32
    {
        const int n  = tid >> 2;
        const int kq = (tid & 3) * 32;
        const unsigned short* srcp = W1bfT + n * HD + kq;
        #pragma unroll
        for (int j = 0; j < 4; ++j) {
            const int c = (kq >> 3) + j;               // 16B chunk index along k
            const int p = c ^ (n & 7);                 // swizzle
            *(bf16x8*)(Wlds + n * HD + p * 8) = *(const bf16x8*)(srcp + j * 8);
        }
    }
    __syncthreads();

    float asv[8], adv[8];
    #pragma unroll
    for (int ct = 0; ct < 8; ++ct) {
        asv[ct] = a_src1[ct * 16 + lm];
        adv[ct] = a_dst1[ct * 16 + lm];
    }

    for (int vb = blockIdx.x; vb < GB; vb += NBK) {
        const int wrow0 = vb * 128 + w * 16;
        const int arow = wrow0 + lm;
        const int g = (arow < N_NODES) ? arow : (N_NODES - 1);
        const float* xrow = emb + (size_t)h[g] * HD;

        f32x4 acc[8];
        #pragma unroll
        for (int ct = 0; ct < 8; ++ct) acc[ct] = (f32x4)0.f;

        #pragma unroll
        for (int ks = 0; ks < 4; ++ks) {
            const int k0 = ks * 32 + lg * 8;
            const float4 u = *(const float4*)(xrow + k0);
            const float4 v = *(const float4*)(xrow + k0 + 4);
            union { bf16x8 b; unsigned x[4]; } t;
            t.x[0] = pack2(u.x, u.y);
            t.x[1] = pack2(u.z, u.w);
            t.x[2] = pack2(v.x, v.y);
            t.x[3] = pack2(v.z, v.w);
            const bf16x8 af = t.b;

            const int c = k0 >> 3;
            const int p = (c ^ (lm & 7)) * 8;          // n&7 == lm&7 for frags
            #pragma unroll
            for (int ct = 0; ct < 8; ++ct) {
                const bf16x8 bfr = *(const bf16x8*)(Wlds + (ct * 16 + lm) * HD + p);
                acc[ct] = __builtin_amdgcn_mfma_f32_16x16x32_bf16(af, bfr, acc[ct], 0, 0, 0);
            }
        }

        // epilogue: dots + direct stores (C/D: col = lm, row = lg*4+reg)
        #pragma unroll
        for (int reg = 0; reg < 4; ++reg) {
            const int row = wrow0 + lg * 4 + reg;
            float s = 0.f, d = 0.f;
            #pragma unroll
            for (int ct = 0; ct < 8; ++ct) {
                s += acc[ct][reg] * asv[ct];
                d += acc[ct][reg] * adv[ct];
            }
            #pragma unroll
            for (int m = 1; m < 16; m <<= 1) {
                s += __shfl_xor(s, m, 64);
                d += __shfl_xor(d, m, 64);
            }
            if (row < N_NODES) {
                unsigned short* dstp = xp1 + (size_t)row * HD;
                #pragma unroll
                for (int ct = 0; ct < 8; ++ct)
                    dstp[ct * 16 + lm] = f2bf(acc[ct][reg]);
                if (lm == 0) {
                    const float sum = s + d;
                    const float l = sum > 0.f ? sum : SLOPE * sum;
                    es1[row] = s;
                    ed1[row] = d;
                    denom1[row] = __expf(l);
                }
            }
        }
    }
    gbar(bar, NBK * 2);

    // ---------------- P3: gather layer 1 (one wave per node) -------------
    for (int i = (int)blockIdx.x * 8 + w; i < N_NODES; i += NBK * 8) {
        const int dcount = min(deg[i], CAP);

        const unsigned pself = ((const unsigned*)(xp1 + (size_t)i * HD))[lane];
        float a0 = bf2f(pself & 0xFFFFu);
        float a1 = bf2f(pself >> 16);

        if (dcount > 0) {
            const float wself = denom1[i];
            const float edv   = ed1[i];
            const int* arow = adj + (size_t)i * CAP;

            int nidx = 0; float nw = 0.f;
            if (lane < dcount) {
                nidx = arow[lane];
                const float lgt = es1[nidx] + edv;
                nw = __expf(lgt > 0.f ? lgt : SLOPE * lgt);
            }
            float dsum = nw;
            #pragma unroll
            for (int m = 32; m > 0; m >>= 1) dsum += __shfl_xor(dsum, m, 64);
            const float inv = 1.f / (wself + dsum);

            a0 *= wself;
            a1 *= wself;

            int j = 0;
            for (; j + 2 <= dcount; j += 2) {
                const int   s0 = __shfl(nidx, j, 64);
                const int   s1 = __shfl(nidx, j + 1, 64);
                const float w0 = __shfl(nw, j, 64);
                const float w1 = __shfl(nw, j + 1, 64);
                const unsigned p0 = ((const unsigned*)(xp1 + (size_t)s0 * HD))[lane];
                const unsigned p1 = ((const unsigned*)(xp1 + (size_t)s1 * HD))[lane];
                a0 += w0 * bf2f(p0 & 0xFFFFu) + w1 * bf2f(p1 & 0xFFFFu);
                a1 += w0 * bf2f(p0 >> 16)     + w1 * bf2f(p1 >> 16);
            }
            if (j < dcount) {
                const int   s0 = __shfl(nidx, j, 64);
                const float w0 = __shfl(nw, j, 64);
                const unsigned p0 = ((const unsigned*)(xp1 + (size_t)s0 * HD))[lane];
                a0 += w0 * bf2f(p0 & 0xFFFFu);
                a1 += w0 * bf2f(p0 >> 16);
            }
            a0 *= inv;
            a1 *= inv;
        }
        // deg==0: softmax collapses, a = x already

        const float o0 = fmaxf(a0 + b1[2 * lane],     0.f);
        const float o1 = fmaxf(a1 + b1[2 * lane + 1], 0.f);

        float part = o0 * W2[2 * lane] + o1 * W2[2 * lane + 1];
        #pragma unroll
        for (int off = 32; off > 0; off >>= 1) part += __shfl_down(part, off, 64);
        if (lane == 0) xp2[i] = part;
    }
    gbar(bar, NBK * 3);

    // ---------------- P4: layer 2 scalars (one thread per node) ----------
    if (gt < N_NODES) {                        // single pass: gstr > N_NODES
        const int i = gt;
        const float xi = xp2[i];
        const int dcount = min(deg[i], CAP);
        if (dcount == 0) {                     // denom=wself, num=wself*xi
            out[i] = xi + b2[0];
            return;
        }

        const float as = a_src2[0], ad = a_dst2[0];
        const float adxi = ad * xi;
        const float s0 = (as + ad) * xi;
        const float l0 = s0 > 0.f ? s0 : SLOPE * s0;
        const float wself = __expf(l0);

        float denom = wself, num = wself * xi;
        const int* arow = adj + (size_t)i * CAP;

        int j = 0;
        for (; j + 2 <= dcount; j += 2) {
            const int2 ss = *(const int2*)(arow + j);
            const float x0 = xp2[ss.x];
            const float x1 = xp2[ss.y];
            float l0e = as * x0 + adxi; l0e = l0e > 0.f ? l0e : SLOPE * l0e;
            float l1e = as * x1 + adxi; l1e = l1e > 0.f ? l1e : SLOPE * l1e;
            const float w0 = __expf(l0e);
            const float w1 = __expf(l1e);
            denom += w0 + w1;
            num   += w0 * x0 + w1 * x1;
        }
        if (j < dcount) {
            const float x0 = xp2[arow[j]];
            float l0e = as * x0 + adxi; l0e = l0e > 0.f ? l0e : SLOPE * l0e;
            const float w0 = __expf(l0e);
            denom += w0;
            num   += w0 * x0;
        }
        out[i] = num / denom + b2[0];
    }
}

extern "C" void kernel_launch(void* const* d_in, const int* in_sizes, int n_in,
                              void* d_out, int out_size, void* d_ws, size_t ws_size,
                              hipStream_t stream)
{
    const int* h   = (const int*)d_in[0];
    const int* ei  = (const int*)d_in[1];
    const int* nt  = (const int*)d_in[2];
    const float* emb    = (const float*)d_in[3];
    const float* W1     = (const float*)d_in[4];
    const float* a_src1 = (const float*)d_in[5];
    const float* a_dst1 = (const float*)d_in[6];
    const float* b1     = (const float*)d_in[7];
    const float* W2     = (const float*)d_in[8];
    const float* a_src2 = (const float*)d_in[9];
    const float* a_dst2 = (const float*)d_in[10];
    const float* b2     = (const float*)d_in[11];
    float* out = (float*)d_out;

    char* ws = (char*)d_ws;
    size_t off = 0;
    unsigned short* xp1 = (unsigned short*)(ws + off); off += (size_t)N_NODES * HD * sizeof(unsigned short);
    float* es1    = (float*)(ws + off); off += (size_t)N_NODES * sizeof(float);
    float* ed1    = (float*)(ws + off); off += (size_t)N_NODES * sizeof(float);
    float* denom1 = (float*)(ws + off); off += (size_t)N_NODES * sizeof(float);
    float* xp2    = (float*)(ws + off); off += (size_t)N_NODES * sizeof(float);
    int*   deg    = (int*)(ws + off);   off += (size_t)N_NODES * sizeof(int);
    unsigned* umask = (unsigned*)(ws + off); off += 3200 * sizeof(unsigned);
    unsigned short* W1bfT = (unsigned short*)(ws + off); off += (size_t)HD * HD * sizeof(unsigned short);
    off = (off + 255) & ~(size_t)255;
    int*   adj    = (int*)(ws + off);   off += (size_t)N_NODES * CAP * sizeof(int);
    off = (off + 255) & ~(size_t)255;
    int*   bar    = (int*)(ws + off);   off += 256;

    hipMemsetAsync(bar, 0, sizeof(int), stream);
    k_mega<<<NBK, 512, 0, stream>>>(
        h, ei, nt, emb, W1, a_src1, a_dst1, b1, W2, a_src2, a_dst2, b2, out,
        xp1, es1, ed1, denom1, xp2, deg, umask, W1bfT, adj, bar);
}

// Round 8
// 262.579 us; speedup vs baseline: 1.7973x; 1.7973x over previous
//
#include <hip/hip_runtime.h>

#define N_NODES 100000
#define N_EDGES 1600000
#define HD 128
#define SLOPE 0.2f
#define NBLK 391            // ceil(N_NODES/256)
#define GB 782              // gemm blocks: ceil(N_NODES/128)
#define EB3 1563            // edge blocks: ceil(N_EDGES/2/512), 2 edges/thread
#define CAP 32              // adjacency bucket capacity (P(deg>32) ~ 1e-19)

typedef __attribute__((ext_vector_type(8))) short bf16x8;
typedef __attribute__((ext_vector_type(4))) float f32x4;

__device__ __forceinline__ unsigned short f2bf(float f) {
    union { float f; unsigned u; } v; v.f = f;
    const unsigned u = v.u + 0x7FFFu + ((v.u >> 16) & 1u);   // RNE
    return (unsigned short)(u >> 16);
}
__device__ __forceinline__ unsigned pack2(float lo, float hi) {
    return (unsigned)f2bf(lo) | ((unsigned)f2bf(hi) << 16);
}
__device__ __forceinline__ float bf2f(unsigned u16) {
    union { unsigned u; float f; } v; v.u = u16 << 16; return v.f;
}

// ---------------------------------------------------------------------------
// K1a: edge bucket-build. Gating reads nt directly (400 KB, L2-resident) —
// k0/umask eliminated. Also sets srcmask bit for every surviving-edge source
// (xp1 rows are only ever read for such nodes).
// deg/srcmask zeroed by hipMemsetAsync before this kernel.
// ---------------------------------------------------------------------------
__global__ __launch_bounds__(512) void k1a_edge(
    const int* __restrict__ ei, const int* __restrict__ nt,
    int* __restrict__ deg, unsigned* __restrict__ srcmask,
    int* __restrict__ adj)
{
    const int t = blockIdx.x * 512 + threadIdx.x;
    const int e0 = t * 2;
    if (e0 >= N_EDGES) return;
    const int2 s2 = *(const int2*)(ei + e0);
    const int2 d2 = *(const int2*)(ei + N_EDGES + e0);
    const bool a0 = (nt[s2.x] == 0) && (nt[d2.x] == 0);
    const bool a1 = (nt[s2.y] == 0) && (nt[d2.y] == 0);
    if (a0) {
        const int sl = atomicAdd(deg + d2.x, 1);
        if (sl < CAP) adj[(size_t)d2.x * CAP + sl] = s2.x;
        atomicOr(srcmask + (s2.x >> 5), 1u << (s2.x & 31));
    }
    if (a1) {
        const int sl = atomicAdd(deg + d2.y, 1);
        if (sl < CAP) adj[(size_t)d2.y * CAP + sl] = s2.y;
        atomicOr(srcmask + (s2.y >> 5), 1u << (s2.y & 31));
    }
}

// ---------------------------------------------------------------------------
// K1b: gemm1 + FUSED deg-0 layer-1 finish. Runs after k1a, so deg/srcmask
// are final. Epilogue computes, per row, the attention dots (s,d) AND the
// deg-0 result p = sum(relu(acc+b1)*W2); deg-0 rows write xp2 directly
// (f32 acc — closer to the f32 reference than the bf16 xp1 round-trip) and
// skip the xp1 store unless the row is a surviving-edge source (~33%).
// W1 f32 -> bf16^T LDS staging is done in-kernel (W1 is 64 KB, L2-hot).
// ---------------------------------------------------------------------------
__global__ __launch_bounds__(512, 8) void k1b_gemm(
    const int* __restrict__ h,
    const float* __restrict__ emb,
    const float* __restrict__ W1,
    const float* __restrict__ a_src1,
    const float* __restrict__ a_dst1,
    const float* __restrict__ b1,
    const float* __restrict__ W2,
    const int* __restrict__ deg,
    const unsigned* __restrict__ srcmask,
    unsigned short* __restrict__ xp1,
    float* __restrict__ es1,
    float* __restrict__ ed1,
    float* __restrict__ denom1,
    float* __restrict__ xp2)
{
    __shared__ unsigned short Wlds[HD * HD];   // 32 KB
    const int tid = threadIdx.x;

    // stage W^T as bf16, converted from f32 W1 in-kernel:
    // thread t -> col n = t>>2, k-quarter (t&3)*32, swizzled chunks of 8
    {
        const int n  = tid >> 2;
        const int kq = (tid & 3) * 32;
        #pragma unroll
        for (int j = 0; j < 4; ++j) {
            union { bf16x8 b; unsigned short u[8]; } tmp;
            #pragma unroll
            for (int kk = 0; kk < 8; ++kk)
                tmp.u[kk] = f2bf(W1[(kq + j * 8 + kk) * HD + n]);
            const int c = (kq >> 3) + j;               // 16B chunk index along k
            const int p = c ^ (n & 7);                 // swizzle
            *(bf16x8*)(Wlds + n * HD + p * 8) = tmp.b;
        }
    }

    const int w   = tid >> 6;                          // 0..7
    const int L   = tid & 63;
    const int lm  = L & 15;
    const int lg  = L >> 4;
    const int wrow0 = blockIdx.x * 128 + w * 16;

    const int arow = wrow0 + lm;
    const int g = (arow < N_NODES) ? arow : (N_NODES - 1);
    const float* xrow = emb + (size_t)h[g] * HD;

    __syncthreads();

    f32x4 acc[8];
    #pragma unroll
    for (int ct = 0; ct < 8; ++ct) acc[ct] = (f32x4)0.f;

    #pragma unroll
    for (int ks = 0; ks < 4; ++ks) {
        const int k0 = ks * 32 + lg * 8;
        const float4 u = *(const float4*)(xrow + k0);
        const float4 v = *(const float4*)(xrow + k0 + 4);
        union { bf16x8 b; unsigned x[4]; } t;
        t.x[0] = pack2(u.x, u.y);
        t.x[1] = pack2(u.z, u.w);
        t.x[2] = pack2(v.x, v.y);
        t.x[3] = pack2(v.z, v.w);
        const bf16x8 af = t.b;

        const int c = k0 >> 3;
        const int p = (c ^ (lm & 7)) * 8;              // n&7 == lm&7 for frag reads
        #pragma unroll
        for (int ct = 0; ct < 8; ++ct) {
            const bf16x8 bfr = *(const bf16x8*)(Wlds + (ct * 16 + lm) * HD + p);
            acc[ct] = __builtin_amdgcn_mfma_f32_16x16x32_bf16(af, bfr, acc[ct], 0, 0, 0);
        }
    }

    // ---- epilogue: loads placed after the K-loop to keep its reg pressure ----
    float asv[8], adv[8], b1v[8], w2v[8];
    #pragma unroll
    for (int ct = 0; ct < 8; ++ct) {
        asv[ct] = a_src1[ct * 16 + lm];
        adv[ct] = a_dst1[ct * 16 + lm];
        b1v[ct] = b1[ct * 16 + lm];
        w2v[ct] = W2[ct * 16 + lm];
    }

    #pragma unroll
    for (int reg = 0; reg < 4; ++reg) {
        const int row = wrow0 + lg * 4 + reg;
        float s = 0.f, d = 0.f, p = 0.f;
        #pragma unroll
        for (int ct = 0; ct < 8; ++ct) {
            const float a = acc[ct][reg];
            s += a * asv[ct];
            d += a * adv[ct];
            p += fmaxf(a + b1v[ct], 0.f) * w2v[ct];
        }
        #pragma unroll
        for (int m = 1; m < 16; m <<= 1) {   // butterfly over the 16 lm lanes
            s += __shfl_xor(s, m, 64);
            d += __shfl_xor(d, m, 64);
            p += __shfl_xor(p, m, 64);
        }
        if (row < N_NODES) {
            const int dcnt = deg[row];                         // broadcast load
            if (dcnt == 0) {
                // layer-1 finished here; xp1 only needed if row is a source
                if (lm == 0) {
                    xp2[row] = p;
                    es1[row] = s;          // needed iff source; cheap either way
                }
                const bool issrc = ((srcmask[row >> 5] >> (row & 31)) & 1u) != 0u;
                if (issrc) {
                    unsigned short* dstp = xp1 + (size_t)row * HD;
                    #pragma unroll
                    for (int ct = 0; ct < 8; ++ct)
                        dstp[ct * 16 + lm] = f2bf(acc[ct][reg]);
                }
            } else {
                unsigned short* dstp = xp1 + (size_t)row * HD;
                #pragma unroll
                for (int ct = 0; ct < 8; ++ct)
                    dstp[ct * 16 + lm] = f2bf(acc[ct][reg]);
                if (lm == 0) {
                    const float sum = s + d;
                    const float l = sum > 0.f ? sum : SLOPE * sum;
                    es1[row] = s;
                    ed1[row] = d;
                    denom1[row] = __expf(l);
                }
            }
        }
    }
}

// ---------------------------------------------------------------------------
// K2: gather layer 1, one wave per node. Deg-0 nodes (~67%) exit after one
// 4B deg read (xp2 already written by k1b). Deg>0: lane-parallel weight
// precompute + 2-way unrolled row-gather + b1 + ReLU + W2 GEMV.
// ---------------------------------------------------------------------------
__global__ __launch_bounds__(256) void k2_gather(
    const unsigned short* __restrict__ xp1, const float* __restrict__ denom1,
    const float* __restrict__ es1, const float* __restrict__ ed1,
    const int* __restrict__ deg, const int* __restrict__ adj,
    const float* __restrict__ b1, const float* __restrict__ W2,
    float* __restrict__ xp2)
{
    const int wid = threadIdx.x >> 6;
    const int lane = threadIdx.x & 63;
    const int i = blockIdx.x * 4 + wid;
    if (i >= N_NODES) return;

    const int dcount = min(deg[i], CAP);
    if (dcount == 0) return;                   // xp2 written by k1b

    const float wself = denom1[i];
    const float edv   = ed1[i];
    const int* arow = adj + (size_t)i * CAP;

    // parallel neighbor metadata (one gather + exp per lane)
    int nidx = 0; float nw = 0.f;
    if (lane < dcount) {
        nidx = arow[lane];
        const float lgt = es1[nidx] + edv;
        nw = __expf(lgt > 0.f ? lgt : SLOPE * lgt);
    }
    float dsum = nw;
    #pragma unroll
    for (int m = 32; m > 0; m >>= 1) dsum += __shfl_xor(dsum, m, 64);
    const float inv = 1.f / (wself + dsum);

    const unsigned pself = ((const unsigned*)(xp1 + (size_t)i * HD))[lane];
    float a0 = wself * bf2f(pself & 0xFFFFu);
    float a1 = wself * bf2f(pself >> 16);

    int j = 0;
    for (; j + 2 <= dcount; j += 2) {
        const int   s0 = __shfl(nidx, j, 64);
        const int   s1 = __shfl(nidx, j + 1, 64);
        const float w0 = __shfl(nw, j, 64);
        const float w1 = __shfl(nw, j + 1, 64);
        const unsigned p0 = ((const unsigned*)(xp1 + (size_t)s0 * HD))[lane];
        const unsigned p1 = ((const unsigned*)(xp1 + (size_t)s1 * HD))[lane];
        a0 += w0 * bf2f(p0 & 0xFFFFu) + w1 * bf2f(p1 & 0xFFFFu);
        a1 += w0 * bf2f(p0 >> 16)     + w1 * bf2f(p1 >> 16);
    }
    if (j < dcount) {
        const int   s0 = __shfl(nidx, j, 64);
        const float w0 = __shfl(nw, j, 64);
        const unsigned p0 = ((const unsigned*)(xp1 + (size_t)s0 * HD))[lane];
        a0 += w0 * bf2f(p0 & 0xFFFFu);
        a1 += w0 * bf2f(p0 >> 16);
    }
    a0 *= inv;
    a1 *= inv;

    const float o0 = fmaxf(a0 + b1[2 * lane],     0.f);
    const float o1 = fmaxf(a1 + b1[2 * lane + 1], 0.f);

    float part = o0 * W2[2 * lane] + o1 * W2[2 * lane + 1];
    #pragma unroll
    for (int off = 32; off > 0; off >>= 1) part += __shfl_down(part, off, 64);
    if (lane == 0) xp2[i] = part;
}

// ---------------------------------------------------------------------------
// K3: layer 2 over scalars (one thread per node) with deg-0 fast path
// (out = xi + b2); deg>0: 2-way unrolled int2 adjacency + independent exps.
// ---------------------------------------------------------------------------
__global__ __launch_bounds__(256) void k3_final(
    const float* __restrict__ xp2, const int* __restrict__ deg,
    const int* __restrict__ adj,
    const float* __restrict__ a_src2, const float* __restrict__ a_dst2,
    const float* __restrict__ b2, float* __restrict__ out)
{
    const int i = blockIdx.x * 256 + threadIdx.x;
    if (i >= N_NODES) return;

    const float xi = xp2[i];
    const int dcount = min(deg[i], CAP);
    if (dcount == 0) {                       // denom=wself, num=wself*xi
        out[i] = xi + b2[0];
        return;
    }

    const float as = a_src2[0], ad = a_dst2[0];
    const float adxi = ad * xi;
    const float s0 = (as + ad) * xi;
    const float l0 = s0 > 0.f ? s0 : SLOPE * s0;
    const float wself = __expf(l0);

    float denom = wself, num = wself * xi;
    const int* arow = adj + (size_t)i * CAP;

    int j = 0;
    for (; j + 2 <= dcount; j += 2) {
        const int2 ss = *(const int2*)(arow + j);
        const float x0 = xp2[ss.x];
        const float x1 = xp2[ss.y];
        float l0e = as * x0 + adxi; l0e = l0e > 0.f ? l0e : SLOPE * l0e;
        float l1e = as * x1 + adxi; l1e = l1e > 0.f ? l1e : SLOPE * l1e;
        const float w0 = __expf(l0e);
        const float w1 = __expf(l1e);
        denom += w0 + w1;
        num   += w0 * x0 + w1 * x1;
    }
    if (j < dcount) {
        const float x0 = xp2[arow[j]];
        float l0e = as * x0 + adxi; l0e = l0e > 0.f ? l0e : SLOPE * l0e;
        const float w0 = __expf(l0e);
        denom += w0;
        num   += w0 * x0;
    }
    out[i] = num / denom + b2[0];
}

extern "C" void kernel_launch(void* const* d_in, const int* in_sizes, int n_in,
                              void* d_out, int out_size, void* d_ws, size_t ws_size,
                              hipStream_t stream)
{
    const int* h   = (const int*)d_in[0];
    const int* ei  = (const int*)d_in[1];
    const int* nt  = (const int*)d_in[2];
    const float* emb    = (const float*)d_in[3];
    const float* W1     = (const float*)d_in[4];
    const float* a_src1 = (const float*)d_in[5];
    const float* a_dst1 = (const float*)d_in[6];
    const float* b1     = (const float*)d_in[7];
    const float* W2     = (const float*)d_in[8];
    const float* a_src2 = (const float*)d_in[9];
    const float* a_dst2 = (const float*)d_in[10];
    const float* b2     = (const float*)d_in[11];
    float* out = (float*)d_out;

    char* ws = (char*)d_ws;
    size_t off = 0;
    unsigned short* xp1 = (unsigned short*)(ws + off); off += (size_t)N_NODES * HD * sizeof(unsigned short);
    float* es1    = (float*)(ws + off); off += (size_t)N_NODES * sizeof(float);
    float* ed1    = (float*)(ws + off); off += (size_t)N_NODES * sizeof(float);
    float* denom1 = (float*)(ws + off); off += (size_t)N_NODES * sizeof(float);
    float* xp2    = (float*)(ws + off); off += (size_t)N_NODES * sizeof(float);
    int*   deg    = (int*)(ws + off);   off += (size_t)N_NODES * sizeof(int);
    unsigned* srcmask = (unsigned*)(ws + off); off += 3200 * sizeof(unsigned);
    off = (off + 255) & ~(size_t)255;
    int*   adj    = (int*)(ws + off);   off += (size_t)N_NODES * CAP * sizeof(int);

    // zero deg + srcmask (adjacent) in one async fill — replaces k0
    hipMemsetAsync(deg, 0, (size_t)(N_NODES + 3200) * sizeof(int), stream);

    k1a_edge<<<EB3, 512, 0, stream>>>(ei, nt, deg, srcmask, adj);
    k1b_gemm<<<GB, 512, 0, stream>>>(
        h, emb, W1, a_src1, a_dst1, b1, W2, deg, srcmask,
        xp1, es1, ed1, denom1, xp2);
    k2_gather<<<(N_NODES + 3) / 4, 256, 0, stream>>>(
        xp1, denom1, es1, ed1, deg, adj, b1, W2, xp2);
    k3_final<<<NBLK, 256, 0, stream>>>(
        xp2, deg, adj, a_src2, a_dst2, b2, out);
}

// Round 9
// 222.372 us; speedup vs baseline: 2.1223x; 1.1808x over previous
//
#include <hip/hip_runtime.h>

#define N_NODES 100000
#define N_EDGES 1600000
#define HD 128
#define SLOPE 0.2f
#define NBLK 391            // ceil(N_NODES/256)
#define GB 782              // gemm blocks: ceil(N_NODES/128)
#define EB3 1563            // edge blocks: ceil(N_EDGES/2/512), 2 edges/thread
#define CAP 32              // adjacency bucket capacity (P(deg>32) ~ 1e-19)
#define SLICE_LD 136        // padded LDS stage stride (shorts)

typedef __attribute__((ext_vector_type(8))) short bf16x8;
typedef __attribute__((ext_vector_type(4))) float f32x4;

__device__ __forceinline__ unsigned short f2bf(float f) {
    union { float f; unsigned u; } v; v.f = f;
    const unsigned u = v.u + 0x7FFFu + ((v.u >> 16) & 1u);   // RNE
    return (unsigned short)(u >> 16);
}
__device__ __forceinline__ unsigned pack2(float lo, float hi) {
    return (unsigned)f2bf(lo) | ((unsigned)f2bf(hi) << 16);
}
__device__ __forceinline__ float bf2f(unsigned u16) {
    union { unsigned u; float f; } v; v.u = u16 << 16; return v.f;
}

// ---------------------------------------------------------------------------
// K0 (restored from round-5): zero deg + srcmask + active bitmask + W1^T
// bf16 pre-convert (64 KB W1 read ONCE, coalesced — round-8's per-block
// in-kernel conversion cost ~50 MB of HBM re-fetch).
// ---------------------------------------------------------------------------
__global__ __launch_bounds__(256) void k0_zero(
    const int* __restrict__ nt, const float* __restrict__ W1,
    int* __restrict__ deg, unsigned* __restrict__ umask,
    unsigned* __restrict__ srcmask, unsigned short* __restrict__ W1bfT)
{
    const int i = blockIdx.x * 256 + threadIdx.x;
    bool act = false;
    if (i < N_NODES) { deg[i] = 0; act = (nt[i] == 0); }
    const unsigned long long bal = __ballot(act);
    const int lane = threadIdx.x & 63;
    if (lane == 0)       umask[i >> 5] = (unsigned)bal;
    else if (lane == 32) umask[i >> 5] = (unsigned)(bal >> 32);
    if (i < 3200) srcmask[i] = 0u;
    if (i < HD * HD) {
        const int n = i >> 7, k = i & 127;
        W1bfT[n * HD + k] = f2bf(W1[k * HD + n]);
    }
}

// ---------------------------------------------------------------------------
// K1a: edge bucket-build (umask-gated, 2 edges/thread) + srcmask atomicOr
// for every surviving-edge source (xp1 rows only read for such nodes).
// ---------------------------------------------------------------------------
__global__ __launch_bounds__(512) void k1a_edge(
    const int* __restrict__ ei, const unsigned* __restrict__ umask,
    int* __restrict__ deg, unsigned* __restrict__ srcmask,
    int* __restrict__ adj)
{
    const int t = blockIdx.x * 512 + threadIdx.x;
    const int e0 = t * 2;
    if (e0 >= N_EDGES) return;
    const int2 s2 = *(const int2*)(ei + e0);
    const int2 d2 = *(const int2*)(ei + N_EDGES + e0);
    const bool a0 =
        (((umask[s2.x >> 5] >> (s2.x & 31)) & (umask[d2.x >> 5] >> (d2.x & 31))) & 1u) != 0u;
    const bool a1 =
        (((umask[s2.y >> 5] >> (s2.y & 31)) & (umask[d2.y >> 5] >> (d2.y & 31))) & 1u) != 0u;
    if (a0) {
        const int sl = atomicAdd(deg + d2.x, 1);
        if (sl < CAP) adj[(size_t)d2.x * CAP + sl] = s2.x;
        atomicOr(srcmask + (s2.x >> 5), 1u << (s2.x & 31));
    }
    if (a1) {
        const int sl = atomicAdd(deg + d2.y, 1);
        if (sl < CAP) adj[(size_t)d2.y * CAP + sl] = s2.y;
        atomicOr(srcmask + (s2.y >> 5), 1u << (s2.y & 31));
    }
}

// ---------------------------------------------------------------------------
// K1b: gemm1 (round-5 mechanics: W1bfT LDS staging, LDS-staged COALESCED
// xp1 store) + deg-0 fused layer-1 finish (runs after k1a, deg final).
// Per row: attention dots (s,d) + deg-0 result p = sum(relu(acc+b1)*W2).
// deg-0 rows write xp2 directly from f32 acc; xp1 row store is skipped
// unless deg>0 or the row is a surviving-edge source (~33% of rows).
// ---------------------------------------------------------------------------
__global__ __launch_bounds__(512, 8) void k1b_gemm(
    const int* __restrict__ h,
    const float* __restrict__ emb,
    const unsigned short* __restrict__ W1bfT,
    const float* __restrict__ a_src1,
    const float* __restrict__ a_dst1,
    const float* __restrict__ b1,
    const float* __restrict__ W2,
    const int* __restrict__ deg,
    const unsigned* __restrict__ srcmask,
    unsigned short* __restrict__ xp1,
    float* __restrict__ es1,
    float* __restrict__ ed1,
    float* __restrict__ denom1,
    float* __restrict__ xp2)
{
    __shared__ unsigned short Wlds[8 * 16 * SLICE_LD];   // 34 KB >= 16384 for W
    const int tid = threadIdx.x;

    // stage W^T from pre-converted W1bfT (coalesced bf16x8, swizzled)
    {
        const int n  = tid >> 2;
        const int kq = (tid & 3) * 32;
        const unsigned short* srcp = W1bfT + n * HD + kq;
        #pragma unroll
        for (int j = 0; j < 4; ++j) {
            const int c = (kq >> 3) + j;               // 16B chunk index along k
            const int p = c ^ (n & 7);                 // swizzle
            *(bf16x8*)(Wlds + n * HD + p * 8) = *(const bf16x8*)(srcp + j * 8);
        }
    }

    const int w   = tid >> 6;                          // 0..7
    const int L   = tid & 63;
    const int lm  = L & 15;
    const int lg  = L >> 4;
    const int wrow0 = blockIdx.x * 128 + w * 16;

    const int arow = wrow0 + lm;
    const int g = (arow < N_NODES) ? arow : (N_NODES - 1);
    const float* xrow = emb + (size_t)h[g] * HD;

    __syncthreads();

    f32x4 acc[8];
    #pragma unroll
    for (int ct = 0; ct < 8; ++ct) acc[ct] = (f32x4)0.f;

    #pragma unroll
    for (int ks = 0; ks < 4; ++ks) {
        const int k0 = ks * 32 + lg * 8;
        const float4 u = *(const float4*)(xrow + k0);
        const float4 v = *(const float4*)(xrow + k0 + 4);
        union { bf16x8 b; unsigned x[4]; } t;
        t.x[0] = pack2(u.x, u.y);
        t.x[1] = pack2(u.z, u.w);
        t.x[2] = pack2(v.x, v.y);
        t.x[3] = pack2(v.z, v.w);
        const bf16x8 af = t.b;

        const int c = k0 >> 3;
        const int p = (c ^ (lm & 7)) * 8;              // n&7 == lm&7 for frag reads
        #pragma unroll
        for (int ct = 0; ct < 8; ++ct) {
            const bf16x8 bfr = *(const bf16x8*)(Wlds + (ct * 16 + lm) * HD + p);
            acc[ct] = __builtin_amdgcn_mfma_f32_16x16x32_bf16(af, bfr, acc[ct], 0, 0, 0);
        }
    }

    // ---- epilogue: dots + deg-0 finish (C/D: col = lm, row = lg*4+reg) ----
    float asv[8], adv[8], b1v[8], w2v[8];
    #pragma unroll
    for (int ct = 0; ct < 8; ++ct) {
        asv[ct] = a_src1[ct * 16 + lm];
        adv[ct] = a_dst1[ct * 16 + lm];
        b1v[ct] = b1[ct * 16 + lm];
        w2v[ct] = W2[ct * 16 + lm];
    }

    #pragma unroll
    for (int reg = 0; reg < 4; ++reg) {
        const int row = wrow0 + lg * 4 + reg;
        float s = 0.f, d = 0.f, p = 0.f;
        #pragma unroll
        for (int ct = 0; ct < 8; ++ct) {
            const float a = acc[ct][reg];
            s += a * asv[ct];
            d += a * adv[ct];
            p += fmaxf(a + b1v[ct], 0.f) * w2v[ct];
        }
        #pragma unroll
        for (int m = 1; m < 16; m <<= 1) {   // butterfly over the 16 lm lanes
            s += __shfl_xor(s, m, 64);
            d += __shfl_xor(d, m, 64);
            p += __shfl_xor(p, m, 64);
        }
        if (row < N_NODES && lm == 0) {
            es1[row] = s;                       // needed for sources either way
            if (deg[row] == 0) {
                xp2[row] = p;                   // layer-1 finished (f32 acc)
            } else {
                const float sum = s + d;
                const float l = sum > 0.f ? sum : SLOPE * sum;
                ed1[row] = d;
                denom1[row] = __expf(l);
            }
        }
    }

    // ---- coalesced xp1 store via LDS transpose stage (W is dead) ----
    __syncthreads();                       // everyone done reading W from Wlds
    unsigned short* slice = Wlds + w * 16 * SLICE_LD;   // 16 rows, padded
    #pragma unroll
    for (int ct = 0; ct < 8; ++ct)
        #pragma unroll
        for (int reg = 0; reg < 4; ++reg)
            slice[(lg * 4 + reg) * SLICE_LD + ct * 16 + lm] = f2bf(acc[ct][reg]);
    __syncthreads();                       // order LDS write->read
    #pragma unroll
    for (int rr = 0; rr < 4; ++rr) {
        const int rl = rr * 4 + lg;        // 0..15
        const int row = wrow0 + rl;
        if (row < N_NODES) {
            // store only rows that will ever be read: deg>0 (self in k2)
            // or surviving-edge source (neighbor gather in k2)
            const bool need = (deg[row] > 0) ||
                (((srcmask[row >> 5] >> (row & 31)) & 1u) != 0u);
            if (need) {
                const bf16x8 vdat = *(const bf16x8*)(slice + rl * SLICE_LD + lm * 8);
                *(bf16x8*)(xp1 + (size_t)row * HD + lm * 8) = vdat;
            }
        }
    }
}

// ---------------------------------------------------------------------------
// K2: gather layer 1, one wave per node. Deg-0 nodes (~67%) exit after one
// 4B deg read (xp2 already written by k1b). Deg>0: lane-parallel weight
// precompute + 2-way unrolled row-gather + b1 + ReLU + W2 GEMV.
// ---------------------------------------------------------------------------
__global__ __launch_bounds__(256) void k2_gather(
    const unsigned short* __restrict__ xp1, const float* __restrict__ denom1,
    const float* __restrict__ es1, const float* __restrict__ ed1,
    const int* __restrict__ deg, const int* __restrict__ adj,
    const float* __restrict__ b1, const float* __restrict__ W2,
    float* __restrict__ xp2)
{
    const int wid = threadIdx.x >> 6;
    const int lane = threadIdx.x & 63;
    const int i = blockIdx.x * 4 + wid;
    if (i >= N_NODES) return;

    const int dcount = min(deg[i], CAP);
    if (dcount == 0) return;                   // xp2 written by k1b

    const float wself = denom1[i];
    const float edv   = ed1[i];
    const int* arow = adj + (size_t)i * CAP;

    // parallel neighbor metadata (one gather + exp per lane)
    int nidx = 0; float nw = 0.f;
    if (lane < dcount) {
        nidx = arow[lane];
        const float lgt = es1[nidx] + edv;
        nw = __expf(lgt > 0.f ? lgt : SLOPE * lgt);
    }
    float dsum = nw;
    #pragma unroll
    for (int m = 32; m > 0; m >>= 1) dsum += __shfl_xor(dsum, m, 64);
    const float inv = 1.f / (wself + dsum);

    const unsigned pself = ((const unsigned*)(xp1 + (size_t)i * HD))[lane];
    float a0 = wself * bf2f(pself & 0xFFFFu);
    float a1 = wself * bf2f(pself >> 16);

    int j = 0;
    for (; j + 2 <= dcount; j += 2) {
        const int   s0 = __shfl(nidx, j, 64);
        const int   s1 = __shfl(nidx, j + 1, 64);
        const float w0 = __shfl(nw, j, 64);
        const float w1 = __shfl(nw, j + 1, 64);
        const unsigned p0 = ((const unsigned*)(xp1 + (size_t)s0 * HD))[lane];
        const unsigned p1 = ((const unsigned*)(xp1 + (size_t)s1 * HD))[lane];
        a0 += w0 * bf2f(p0 & 0xFFFFu) + w1 * bf2f(p1 & 0xFFFFu);
        a1 += w0 * bf2f(p0 >> 16)     + w1 * bf2f(p1 >> 16);
    }
    if (j < dcount) {
        const int   s0 = __shfl(nidx, j, 64);
        const float w0 = __shfl(nw, j, 64);
        const unsigned p0 = ((const unsigned*)(xp1 + (size_t)s0 * HD))[lane];
        a0 += w0 * bf2f(p0 & 0xFFFFu);
        a1 += w0 * bf2f(p0 >> 16);
    }
    a0 *= inv;
    a1 *= inv;

    const float o0 = fmaxf(a0 + b1[2 * lane],     0.f);
    const float o1 = fmaxf(a1 + b1[2 * lane + 1], 0.f);

    float part = o0 * W2[2 * lane] + o1 * W2[2 * lane + 1];
    #pragma unroll
    for (int off = 32; off > 0; off >>= 1) part += __shfl_down(part, off, 64);
    if (lane == 0) xp2[i] = part;
}

// ---------------------------------------------------------------------------
// K3: layer 2 over scalars (one thread per node) with deg-0 fast path
// (out = xi + b2); deg>0: 2-way unrolled int2 adjacency + independent exps.
// ---------------------------------------------------------------------------
__global__ __launch_bounds__(256) void k3_final(
    const float* __restrict__ xp2, const int* __restrict__ deg,
    const int* __restrict__ adj,
    const float* __restrict__ a_src2, const float* __restrict__ a_dst2,
    const float* __restrict__ b2, float* __restrict__ out)
{
    const int i = blockIdx.x * 256 + threadIdx.x;
    if (i >= N_NODES) return;

    const float xi = xp2[i];
    const int dcount = min(deg[i], CAP);
    if (dcount == 0) {                       // denom=wself, num=wself*xi
        out[i] = xi + b2[0];
        return;
    }

    const float as = a_src2[0], ad = a_dst2[0];
    const float adxi = ad * xi;
    const float s0 = (as + ad) * xi;
    const float l0 = s0 > 0.f ? s0 : SLOPE * s0;
    const float wself = __expf(l0);

    float denom = wself, num = wself * xi;
    const int* arow = adj + (size_t)i * CAP;

    int j = 0;
    for (; j + 2 <= dcount; j += 2) {
        const int2 ss = *(const int2*)(arow + j);
        const float x0 = xp2[ss.x];
        const float x1 = xp2[ss.y];
        float l0e = as * x0 + adxi; l0e = l0e > 0.f ? l0e : SLOPE * l0e;
        float l1e = as * x1 + adxi; l1e = l1e > 0.f ? l1e : SLOPE * l1e;
        const float w0 = __expf(l0e);
        const float w1 = __expf(l1e);
        denom += w0 + w1;
        num   += w0 * x0 + w1 * x1;
    }
    if (j < dcount) {
        const float x0 = xp2[arow[j]];
        float l0e = as * x0 + adxi; l0e = l0e > 0.f ? l0e : SLOPE * l0e;
        const float w0 = __expf(l0e);
        denom += w0;
        num   += w0 * x0;
    }
    out[i] = num / denom + b2[0];
}

extern "C" void kernel_launch(void* const* d_in, const int* in_sizes, int n_in,
                              void* d_out, int out_size, void* d_ws, size_t ws_size,
                              hipStream_t stream)
{
    const int* h   = (const int*)d_in[0];
    const int* ei  = (const int*)d_in[1];
    const int* nt  = (const int*)d_in[2];
    const float* emb    = (const float*)d_in[3];
    const float* W1     = (const float*)d_in[4];
    const float* a_src1 = (const float*)d_in[5];
    const float* a_dst1 = (const float*)d_in[6];
    const float* b1     = (const float*)d_in[7];
    const float* W2     = (const float*)d_in[8];
    const float* a_src2 = (const float*)d_in[9];
    const float* a_dst2 = (const float*)d_in[10];
    const float* b2     = (const float*)d_in[11];
    float* out = (float*)d_out;

    char* ws = (char*)d_ws;
    size_t off = 0;
    unsigned short* xp1 = (unsigned short*)(ws + off); off += (size_t)N_NODES * HD * sizeof(unsigned short);
    float* es1    = (float*)(ws + off); off += (size_t)N_NODES * sizeof(float);
    float* ed1    = (float*)(ws + off); off += (size_t)N_NODES * sizeof(float);
    float* denom1 = (float*)(ws + off); off += (size_t)N_NODES * sizeof(float);
    float* xp2    = (float*)(ws + off); off += (size_t)N_NODES * sizeof(float);
    int*   deg    = (int*)(ws + off);   off += (size_t)N_NODES * sizeof(int);
    unsigned* umask   = (unsigned*)(ws + off); off += 3200 * sizeof(unsigned);
    unsigned* srcmask = (unsigned*)(ws + off); off += 3200 * sizeof(unsigned);
    unsigned short* W1bfT = (unsigned short*)(ws + off); off += (size_t)HD * HD * sizeof(unsigned short);
    off = (off + 255) & ~(size_t)255;
    int*   adj    = (int*)(ws + off);   off += (size_t)N_NODES * CAP * sizeof(int);

    k0_zero<<<NBLK, 256, 0, stream>>>(nt, W1, deg, umask, srcmask, W1bfT);
    k1a_edge<<<EB3, 512, 0, stream>>>(ei, umask, deg, srcmask, adj);
    k1b_gemm<<<GB, 512, 0, stream>>>(
        h, emb, W1bfT, a_src1, a_dst1, b1, W2, deg, srcmask,
        xp1, es1, ed1, denom1, xp2);
    k2_gather<<<(N_NODES + 3) / 4, 256, 0, stream>>>(
        xp1, denom1, es1, ed1, deg, adj, b1, W2, xp2);
    k3_final<<<NBLK, 256, 0, stream>>>(
        xp2, deg, adj, a_src2, a_dst2, b2, out);
}

// Round 10
// 176.297 us; speedup vs baseline: 2.6769x; 1.2613x over previous
//
#include <hip/hip_runtime.h>

#define N_NODES 100000
#define N_EDGES 1600000
#define HD 128
#define SLOPE 0.2f
#define NBLK 391            // ceil(N_NODES/256)
#define GB 782              // gemm blocks: ceil(N_NODES/128)
#define EB3 1563            // edge blocks: ceil(N_EDGES/2/512), 2 edges/thread
#define CAP 32              // adjacency bucket capacity (P(deg>32) ~ 1e-19)
#define SLICE_LD 136        // padded LDS stage stride (shorts)
#define K2B 2048            // k2 persistent blocks (8192 waves grid-striding)

typedef __attribute__((ext_vector_type(8))) short bf16x8;
typedef __attribute__((ext_vector_type(4))) float f32x4;

__device__ __forceinline__ unsigned short f2bf(float f) {
    union { float f; unsigned u; } v; v.f = f;
    const unsigned u = v.u + 0x7FFFu + ((v.u >> 16) & 1u);   // RNE
    return (unsigned short)(u >> 16);
}
__device__ __forceinline__ unsigned pack2(float lo, float hi) {
    return (unsigned)f2bf(lo) | ((unsigned)f2bf(hi) << 16);
}
__device__ __forceinline__ float bf2f(unsigned u16) {
    union { unsigned u; float f; } v; v.u = u16 << 16; return v.f;
}

// ---------------------------------------------------------------------------
// K0: zero deg + node-active bitmask + W1^T bf16 convert. (round-5 exact)
// ---------------------------------------------------------------------------
__global__ __launch_bounds__(256) void k0_zero(
    const int* __restrict__ nt, const float* __restrict__ W1,
    int* __restrict__ deg, unsigned* __restrict__ umask,
    unsigned short* __restrict__ W1bfT)
{
    const int i = blockIdx.x * 256 + threadIdx.x;
    bool act = false;
    if (i < N_NODES) { deg[i] = 0; act = (nt[i] == 0); }
    const unsigned long long bal = __ballot(act);
    const int lane = threadIdx.x & 63;
    if (lane == 0)       umask[i >> 5] = (unsigned)bal;
    else if (lane == 32) umask[i >> 5] = (unsigned)(bal >> 32);
    if (i < HD * HD) {
        const int n = i >> 7, k = i & 127;
        W1bfT[n * HD + k] = f2bf(W1[k * HD + n]);
    }
}

// ---------------------------------------------------------------------------
// K1a: edge bucket-build, 2 edges/thread via int2 loads. (round-5 exact)
// ---------------------------------------------------------------------------
__global__ __launch_bounds__(512) void k1a_edge(
    const int* __restrict__ ei, const unsigned* __restrict__ umask,
    int* __restrict__ deg, int* __restrict__ adj)
{
    const int t = blockIdx.x * 512 + threadIdx.x;
    const int e0 = t * 2;
    if (e0 >= N_EDGES) return;
    const int2 s2 = *(const int2*)(ei + e0);
    const int2 d2 = *(const int2*)(ei + N_EDGES + e0);
    const bool a0 =
        (((umask[s2.x >> 5] >> (s2.x & 31)) & (umask[d2.x >> 5] >> (d2.x & 31))) & 1u) != 0u;
    const bool a1 =
        (((umask[s2.y >> 5] >> (s2.y & 31)) & (umask[d2.y >> 5] >> (d2.y & 31))) & 1u) != 0u;
    if (a0) {
        const int sl = atomicAdd(deg + d2.x, 1);
        if (sl < CAP) adj[(size_t)d2.x * CAP + sl] = s2.x;
    }
    if (a1) {
        const int sl = atomicAdd(deg + d2.y, 1);
        if (sl < CAP) adj[(size_t)d2.y * CAP + sl] = s2.y;
    }
}

// ---------------------------------------------------------------------------
// K1b: gemm1, LDS-staged coalesced xp1 store. (round-5 exact)
// ---------------------------------------------------------------------------
__global__ __launch_bounds__(512, 8) void k1b_gemm(
    const int* __restrict__ h,
    const float* __restrict__ emb,
    const unsigned short* __restrict__ W1bfT,
    const float* __restrict__ a_src1,
    const float* __restrict__ a_dst1,
    unsigned short* __restrict__ xp1,
    float* __restrict__ es1,
    float* __restrict__ ed1,
    float* __restrict__ denom1)
{
    __shared__ unsigned short Wlds[8 * 16 * SLICE_LD];   // 34 KB >= 16384 for W
    const int tid = threadIdx.x;

    // stage W^T: thread t -> col n = t>>2, k-quarter (t&3)*32, swizzled
    {
        const int n  = tid >> 2;
        const int kq = (tid & 3) * 32;
        const unsigned short* src = W1bfT + n * HD + kq;
        #pragma unroll
        for (int j = 0; j < 4; ++j) {
            const int c = (kq >> 3) + j;               // 16B chunk index along k
            const int p = c ^ (n & 7);                 // swizzle
            *(bf16x8*)(Wlds + n * HD + p * 8) = *(const bf16x8*)(src + j * 8);
        }
    }

    const int w   = tid >> 6;                          // 0..7
    const int L   = tid & 63;
    const int lm  = L & 15;
    const int lg  = L >> 4;
    const int wrow0 = blockIdx.x * 128 + w * 16;

    const int arow = wrow0 + lm;
    const int g = (arow < N_NODES) ? arow : (N_NODES - 1);
    const float* xrow = emb + (size_t)h[g] * HD;

    __syncthreads();

    f32x4 acc[8];
    #pragma unroll
    for (int ct = 0; ct < 8; ++ct) acc[ct] = (f32x4)0.f;

    #pragma unroll
    for (int ks = 0; ks < 4; ++ks) {
        const int k0 = ks * 32 + lg * 8;
        const float4 u = *(const float4*)(xrow + k0);
        const float4 v = *(const float4*)(xrow + k0 + 4);
        union { bf16x8 b; unsigned x[4]; } t;
        t.x[0] = pack2(u.x, u.y);
        t.x[1] = pack2(u.z, u.w);
        t.x[2] = pack2(v.x, v.y);
        t.x[3] = pack2(v.z, v.w);
        const bf16x8 af = t.b;

        const int c = k0 >> 3;
        const int p = (c ^ (lm & 7)) * 8;              // n&7 == lm&7 for frag reads
        #pragma unroll
        for (int ct = 0; ct < 8; ++ct) {
            const bf16x8 bfr = *(const bf16x8*)(Wlds + (ct * 16 + lm) * HD + p);
            acc[ct] = __builtin_amdgcn_mfma_f32_16x16x32_bf16(af, bfr, acc[ct], 0, 0, 0);
        }
    }

    // attention dots (C/D: col = lm, row-in-tile = lg*4+reg)
    float asv[8], adv[8];
    #pragma unroll
    for (int ct = 0; ct < 8; ++ct) {
        asv[ct] = a_src1[ct * 16 + lm];
        adv[ct] = a_dst1[ct * 16 + lm];
    }

    #pragma unroll
    for (int reg = 0; reg < 4; ++reg) {
        const int row = wrow0 + lg * 4 + reg;
        float s = 0.f, d = 0.f;
        #pragma unroll
        for (int ct = 0; ct < 8; ++ct) {
            s += acc[ct][reg] * asv[ct];
            d += acc[ct][reg] * adv[ct];
        }
        #pragma unroll
        for (int m = 1; m < 16; m <<= 1) {   // reduce over the 16 lm lanes
            s += __shfl_xor(s, m, 64);
            d += __shfl_xor(d, m, 64);
        }
        if (row < N_NODES && lm == 0) {
            const float sum = s + d;
            const float l = sum > 0.f ? sum : SLOPE * sum;
            es1[row] = s;
            ed1[row] = d;
            denom1[row] = __expf(l);
        }
    }

    // ---- coalesced xp1 store via LDS transpose stage (W is dead) ----
    __syncthreads();                       // everyone done reading W from Wlds
    unsigned short* slice = Wlds + w * 16 * SLICE_LD;   // 16 rows, padded
    #pragma unroll
    for (int ct = 0; ct < 8; ++ct)
        #pragma unroll
        for (int reg = 0; reg < 4; ++reg)
            slice[(lg * 4 + reg) * SLICE_LD + ct * 16 + lm] = f2bf(acc[ct][reg]);
    __syncthreads();                       // order intra-wave LDS write->read
    #pragma unroll
    for (int rr = 0; rr < 4; ++rr) {
        const int rl = rr * 4 + lg;        // 0..15
        const int row = wrow0 + rl;
        if (row < N_NODES) {
            const bf16x8 vdat = *(const bf16x8*)(slice + rl * SLICE_LD + lm * 8);
            *(bf16x8*)(xp1 + (size_t)row * HD + lm * 8) = vdat;
        }
    }
}

// ---------------------------------------------------------------------------
// K2: gather layer 1, one wave per node — round-5 body, but launched as a
// 2048-block persistent grid (8192 waves grid-striding over nodes) instead
// of 25000 one-shot blocks: removes ~12x of block launch/ramp overhead.
// ---------------------------------------------------------------------------
__global__ __launch_bounds__(256) void k2_gather(
    const unsigned short* __restrict__ xp1, const float* __restrict__ denom1,
    const float* __restrict__ es1, const float* __restrict__ ed1,
    const int* __restrict__ deg, const int* __restrict__ adj,
    const float* __restrict__ b1, const float* __restrict__ W2,
    float* __restrict__ xp2)
{
    const int wid = threadIdx.x >> 6;
    const int lane = threadIdx.x & 63;
    const float b1a = b1[2 * lane], b1b = b1[2 * lane + 1];
    const float w2a = W2[2 * lane], w2b = W2[2 * lane + 1];

    for (int i = blockIdx.x * 4 + wid; i < N_NODES; i += K2B * 4) {
        const int dcount = min(deg[i], CAP);

        const unsigned pself = ((const unsigned*)(xp1 + (size_t)i * HD))[lane];
        float a0 = bf2f(pself & 0xFFFFu);
        float a1 = bf2f(pself >> 16);

        if (dcount > 0) {
            const float wself = denom1[i];
            const float edv   = ed1[i];
            const int* arow = adj + (size_t)i * CAP;

            // parallel neighbor metadata (one gather + exp per lane)
            int nidx = 0; float nw = 0.f;
            if (lane < dcount) {
                nidx = arow[lane];
                const float lgt = es1[nidx] + edv;
                nw = __expf(lgt > 0.f ? lgt : SLOPE * lgt);
            }
            float dsum = nw;
            #pragma unroll
            for (int m = 32; m > 0; m >>= 1) dsum += __shfl_xor(dsum, m, 64);
            const float inv = 1.f / (wself + dsum);

            a0 *= wself;
            a1 *= wself;

            int j = 0;
            for (; j + 2 <= dcount; j += 2) {
                const int   s0 = __shfl(nidx, j, 64);
                const int   s1 = __shfl(nidx, j + 1, 64);
                const float w0 = __shfl(nw, j, 64);
                const float w1 = __shfl(nw, j + 1, 64);
                const unsigned p0 = ((const unsigned*)(xp1 + (size_t)s0 * HD))[lane];
                const unsigned p1 = ((const unsigned*)(xp1 + (size_t)s1 * HD))[lane];
                a0 += w0 * bf2f(p0 & 0xFFFFu) + w1 * bf2f(p1 & 0xFFFFu);
                a1 += w0 * bf2f(p0 >> 16)     + w1 * bf2f(p1 >> 16);
            }
            if (j < dcount) {
                const int   s0 = __shfl(nidx, j, 64);
                const float w0 = __shfl(nw, j, 64);
                const unsigned p0 = ((const unsigned*)(xp1 + (size_t)s0 * HD))[lane];
                a0 += w0 * bf2f(p0 & 0xFFFFu);
                a1 += w0 * bf2f(p0 >> 16);
            }
            a0 *= inv;
            a1 *= inv;
        }
        // deg==0: denom == wself, numerator == wself * x  ->  a = x (already)

        const float o0 = fmaxf(a0 + b1a, 0.f);
        const float o1 = fmaxf(a1 + b1b, 0.f);

        float part = o0 * w2a + o1 * w2b;
        #pragma unroll
        for (int off = 32; off > 0; off >>= 1) part += __shfl_down(part, off, 64);
        if (lane == 0) xp2[i] = part;
    }
}

// ---------------------------------------------------------------------------
// K3: layer 2 over scalars with deg-0 fast path. (round-5 exact)
// ---------------------------------------------------------------------------
__global__ __launch_bounds__(256) void k3_final(
    const float* __restrict__ xp2, const int* __restrict__ deg,
    const int* __restrict__ adj,
    const float* __restrict__ a_src2, const float* __restrict__ a_dst2,
    const float* __restrict__ b2, float* __restrict__ out)
{
    const int i = blockIdx.x * 256 + threadIdx.x;
    if (i >= N_NODES) return;

    const float xi = xp2[i];
    const int dcount = min(deg[i], CAP);
    if (dcount == 0) {                       // denom=wself, num=wself*xi
        out[i] = xi + b2[0];
        return;
    }

    const float as = a_src2[0], ad = a_dst2[0];
    const float adxi = ad * xi;
    const float s0 = (as + ad) * xi;
    const float l0 = s0 > 0.f ? s0 : SLOPE * s0;
    const float wself = __expf(l0);

    float denom = wself, num = wself * xi;
    const int* arow = adj + (size_t)i * CAP;

    int j = 0;
    for (; j + 2 <= dcount; j += 2) {
        const int2 ss = *(const int2*)(arow + j);
        const float x0 = xp2[ss.x];
        const float x1 = xp2[ss.y];
        float l0e = as * x0 + adxi; l0e = l0e > 0.f ? l0e : SLOPE * l0e;
        float l1e = as * x1 + adxi; l1e = l1e > 0.f ? l1e : SLOPE * l1e;
        const float w0 = __expf(l0e);
        const float w1 = __expf(l1e);
        denom += w0 + w1;
        num   += w0 * x0 + w1 * x1;
    }
    if (j < dcount) {
        const float x0 = xp2[arow[j]];
        float l0e = as * x0 + adxi; l0e = l0e > 0.f ? l0e : SLOPE * l0e;
        const float w0 = __expf(l0e);
        denom += w0;
        num   += w0 * x0;
    }
    out[i] = num / denom + b2[0];
}

extern "C" void kernel_launch(void* const* d_in, const int* in_sizes, int n_in,
                              void* d_out, int out_size, void* d_ws, size_t ws_size,
                              hipStream_t stream)
{
    const int* h   = (const int*)d_in[0];
    const int* ei  = (const int*)d_in[1];
    const int* nt  = (const int*)d_in[2];
    const float* emb    = (const float*)d_in[3];
    const float* W1     = (const float*)d_in[4];
    const float* a_src1 = (const float*)d_in[5];
    const float* a_dst1 = (const float*)d_in[6];
    const float* b1     = (const float*)d_in[7];
    const float* W2     = (const float*)d_in[8];
    const float* a_src2 = (const float*)d_in[9];
    const float* a_dst2 = (const float*)d_in[10];
    const float* b2     = (const float*)d_in[11];
    float* out = (float*)d_out;

    char* ws = (char*)d_ws;
    size_t off = 0;
    unsigned short* xp1 = (unsigned short*)(ws + off); off += (size_t)N_NODES * HD * sizeof(unsigned short);
    float* es1    = (float*)(ws + off); off += (size_t)N_NODES * sizeof(float);
    float* ed1    = (float*)(ws + off); off += (size_t)N_NODES * sizeof(float);
    float* denom1 = (float*)(ws + off); off += (size_t)N_NODES * sizeof(float);
    float* xp2    = (float*)(ws + off); off += (size_t)N_NODES * sizeof(float);
    int*   deg    = (int*)(ws + off);   off += (size_t)N_NODES * sizeof(int);
    unsigned* umask = (unsigned*)(ws + off); off += 3200 * sizeof(unsigned);
    unsigned short* W1bfT = (unsigned short*)(ws + off); off += (size_t)HD * HD * sizeof(unsigned short);
    off = (off + 255) & ~(size_t)255;
    int*   adj    = (int*)(ws + off);   off += (size_t)N_NODES * CAP * sizeof(int);

    k0_zero<<<NBLK, 256, 0, stream>>>(nt, W1, deg, umask, W1bfT);
    k1a_edge<<<EB3, 512, 0, stream>>>(ei, umask, deg, adj);
    k1b_gemm<<<GB, 512, 0, stream>>>(
        h, emb, W1bfT, a_src1, a_dst1, xp1, es1, ed1, denom1);
    k2_gather<<<K2B, 256, 0, stream>>>(
        xp1, denom1, es1, ed1, deg, adj, b1, W2, xp2);
    k3_final<<<NBLK, 256, 0, stream>>>(
        xp2, deg, adj, a_src2, a_dst2, b2, out);
}

// Round 11
// 173.338 us; speedup vs baseline: 2.7226x; 1.0171x over previous
//
#include <hip/hip_runtime.h>

#define N_NODES 100000
#define N_EDGES 1600000
#define HD 128
#define SLOPE 0.2f
#define NBLK 391            // ceil(N_NODES/256)
#define GB 782              // gemm blocks: ceil(N_NODES/128)
#define EB3 1563            // edge blocks: ceil(N_EDGES/2/512), 2 edges/thread
#define CAP 32              // adjacency bucket capacity (P(deg>32) ~ 1e-19)
#define SLICE_LD 136        // padded LDS stage stride (shorts)
#define K2B 2048            // k2 persistent blocks (8192 waves grid-striding)

typedef __attribute__((ext_vector_type(8))) short bf16x8;
typedef __attribute__((ext_vector_type(4))) float f32x4;

__device__ __forceinline__ unsigned short f2bf(float f) {
    union { float f; unsigned u; } v; v.f = f;
    const unsigned u = v.u + 0x7FFFu + ((v.u >> 16) & 1u);   // RNE
    return (unsigned short)(u >> 16);
}
__device__ __forceinline__ unsigned pack2(float lo, float hi) {
    return (unsigned)f2bf(lo) | ((unsigned)f2bf(hi) << 16);
}
__device__ __forceinline__ float bf2f(unsigned u16) {
    union { unsigned u; float f; } v; v.u = u16 << 16; return v.f;
}

// ---------------------------------------------------------------------------
// K0: zero deg + node-active bitmask + W1^T bf16 convert. (round-5 exact)
// ---------------------------------------------------------------------------
__global__ __launch_bounds__(256) void k0_zero(
    const int* __restrict__ nt, const float* __restrict__ W1,
    int* __restrict__ deg, unsigned* __restrict__ umask,
    unsigned short* __restrict__ W1bfT)
{
    const int i = blockIdx.x * 256 + threadIdx.x;
    bool act = false;
    if (i < N_NODES) { deg[i] = 0; act = (nt[i] == 0); }
    const unsigned long long bal = __ballot(act);
    const int lane = threadIdx.x & 63;
    if (lane == 0)       umask[i >> 5] = (unsigned)bal;
    else if (lane == 32) umask[i >> 5] = (unsigned)(bal >> 32);
    if (i < HD * HD) {
        const int n = i >> 7, k = i & 127;
        W1bfT[n * HD + k] = f2bf(W1[k * HD + n]);
    }
}

// ---------------------------------------------------------------------------
// K1: FUSED edge bucket-build + gemm1 — heterogeneous grid, the round-2/4
// pattern both measured at ~43us (≈ split sum minus one dispatch overhead).
// Blocks [0,EB3): 2 edges/thread via int2 (round-10 k1a body, exact).
// Blocks [EB3,EB3+GB): gemm with LDS-staged coalesced xp1 store (round-10
// k1b body, exact). Edge blocks drain first at full width, gemm backfills.
// ---------------------------------------------------------------------------
__global__ __launch_bounds__(512, 8) void k1_fused(
    const int* __restrict__ ei,
    const unsigned* __restrict__ umask,
    int* __restrict__ deg,
    int* __restrict__ adj,
    const int* __restrict__ h,
    const float* __restrict__ emb,
    const unsigned short* __restrict__ W1bfT,
    const float* __restrict__ a_src1,
    const float* __restrict__ a_dst1,
    unsigned short* __restrict__ xp1,
    float* __restrict__ es1,
    float* __restrict__ ed1,
    float* __restrict__ denom1)
{
    __shared__ unsigned short Wlds[8 * 16 * SLICE_LD];   // 34 KB
    const int tid = threadIdx.x;

    if (blockIdx.x < EB3) {
        // ------------------------- edge path -------------------------
        const int t = blockIdx.x * 512 + tid;
        const int e0 = t * 2;
        if (e0 >= N_EDGES) return;
        const int2 s2 = *(const int2*)(ei + e0);
        const int2 d2 = *(const int2*)(ei + N_EDGES + e0);
        const bool a0 =
            (((umask[s2.x >> 5] >> (s2.x & 31)) & (umask[d2.x >> 5] >> (d2.x & 31))) & 1u) != 0u;
        const bool a1 =
            (((umask[s2.y >> 5] >> (s2.y & 31)) & (umask[d2.y >> 5] >> (d2.y & 31))) & 1u) != 0u;
        if (a0) {
            const int sl = atomicAdd(deg + d2.x, 1);
            if (sl < CAP) adj[(size_t)d2.x * CAP + sl] = s2.x;
        }
        if (a1) {
            const int sl = atomicAdd(deg + d2.y, 1);
            if (sl < CAP) adj[(size_t)d2.y * CAP + sl] = s2.y;
        }
        return;
    }
    const int vb = blockIdx.x - EB3;           // gemm tile index 0..GB-1

    // ------------------------- gemm path (round-10 k1b exact) -------------
    // stage W^T: thread t -> col n = t>>2, k-quarter (t&3)*32, swizzled
    {
        const int n  = tid >> 2;
        const int kq = (tid & 3) * 32;
        const unsigned short* src = W1bfT + n * HD + kq;
        #pragma unroll
        for (int j = 0; j < 4; ++j) {
            const int c = (kq >> 3) + j;               // 16B chunk index along k
            const int p = c ^ (n & 7);                 // swizzle
            *(bf16x8*)(Wlds + n * HD + p * 8) = *(const bf16x8*)(src + j * 8);
        }
    }

    const int w   = tid >> 6;                          // 0..7
    const int L   = tid & 63;
    const int lm  = L & 15;
    const int lg  = L >> 4;
    const int wrow0 = vb * 128 + w * 16;

    const int arow = wrow0 + lm;
    const int g = (arow < N_NODES) ? arow : (N_NODES - 1);
    const float* xrow = emb + (size_t)h[g] * HD;

    __syncthreads();

    f32x4 acc[8];
    #pragma unroll
    for (int ct = 0; ct < 8; ++ct) acc[ct] = (f32x4)0.f;

    #pragma unroll
    for (int ks = 0; ks < 4; ++ks) {
        const int k0 = ks * 32 + lg * 8;
        const float4 u = *(const float4*)(xrow + k0);
        const float4 v = *(const float4*)(xrow + k0 + 4);
        union { bf16x8 b; unsigned x[4]; } t;
        t.x[0] = pack2(u.x, u.y);
        t.x[1] = pack2(u.z, u.w);
        t.x[2] = pack2(v.x, v.y);
        t.x[3] = pack2(v.z, v.w);
        const bf16x8 af = t.b;

        const int c = k0 >> 3;
        const int p = (c ^ (lm & 7)) * 8;              // n&7 == lm&7 for frag reads
        #pragma unroll
        for (int ct = 0; ct < 8; ++ct) {
            const bf16x8 bfr = *(const bf16x8*)(Wlds + (ct * 16 + lm) * HD + p);
            acc[ct] = __builtin_amdgcn_mfma_f32_16x16x32_bf16(af, bfr, acc[ct], 0, 0, 0);
        }
    }

    // attention dots (C/D: col = lm, row-in-tile = lg*4+reg)
    float asv[8], adv[8];
    #pragma unroll
    for (int ct = 0; ct < 8; ++ct) {
        asv[ct] = a_src1[ct * 16 + lm];
        adv[ct] = a_dst1[ct * 16 + lm];
    }

    #pragma unroll
    for (int reg = 0; reg < 4; ++reg) {
        const int row = wrow0 + lg * 4 + reg;
        float s = 0.f, d = 0.f;
        #pragma unroll
        for (int ct = 0; ct < 8; ++ct) {
            s += acc[ct][reg] * asv[ct];
            d += acc[ct][reg] * adv[ct];
        }
        #pragma unroll
        for (int m = 1; m < 16; m <<= 1) {   // reduce over the 16 lm lanes
            s += __shfl_xor(s, m, 64);
            d += __shfl_xor(d, m, 64);
        }
        if (row < N_NODES && lm == 0) {
            const float sum = s + d;
            const float l = sum > 0.f ? sum : SLOPE * sum;
            es1[row] = s;
            ed1[row] = d;
            denom1[row] = __expf(l);
        }
    }

    // ---- coalesced xp1 store via LDS transpose stage (W is dead) ----
    __syncthreads();                       // everyone done reading W from Wlds
    unsigned short* slice = Wlds + w * 16 * SLICE_LD;   // 16 rows, padded
    #pragma unroll
    for (int ct = 0; ct < 8; ++ct)
        #pragma unroll
        for (int reg = 0; reg < 4; ++reg)
            slice[(lg * 4 + reg) * SLICE_LD + ct * 16 + lm] = f2bf(acc[ct][reg]);
    __syncthreads();                       // order intra-wave LDS write->read
    #pragma unroll
    for (int rr = 0; rr < 4; ++rr) {
        const int rl = rr * 4 + lg;        // 0..15
        const int row = wrow0 + rl;
        if (row < N_NODES) {
            const bf16x8 vdat = *(const bf16x8*)(slice + rl * SLICE_LD + lm * 8);
            *(bf16x8*)(xp1 + (size_t)row * HD + lm * 8) = vdat;
        }
    }
}

// ---------------------------------------------------------------------------
// K2: gather layer 1, persistent 2048-block grid (round-10 exact) + one
// addition: deg-0 nodes also get their FINAL output written here
// (out = xp2 + b2 — k3's deg-0 path), so k3 can skip them entirely.
// ---------------------------------------------------------------------------
__global__ __launch_bounds__(256) void k2_gather(
    const unsigned short* __restrict__ xp1, const float* __restrict__ denom1,
    const float* __restrict__ es1, const float* __restrict__ ed1,
    const int* __restrict__ deg, const int* __restrict__ adj,
    const float* __restrict__ b1, const float* __restrict__ W2,
    const float* __restrict__ b2,
    float* __restrict__ xp2, float* __restrict__ out)
{
    const int wid = threadIdx.x >> 6;
    const int lane = threadIdx.x & 63;
    const float b1a = b1[2 * lane], b1b = b1[2 * lane + 1];
    const float w2a = W2[2 * lane], w2b = W2[2 * lane + 1];
    const float b2v = b2[0];

    for (int i = blockIdx.x * 4 + wid; i < N_NODES; i += K2B * 4) {
        const int dcount = min(deg[i], CAP);

        const unsigned pself = ((const unsigned*)(xp1 + (size_t)i * HD))[lane];
        float a0 = bf2f(pself & 0xFFFFu);
        float a1 = bf2f(pself >> 16);

        if (dcount > 0) {
            const float wself = denom1[i];
            const float edv   = ed1[i];
            const int* arow = adj + (size_t)i * CAP;

            // parallel neighbor metadata (one gather + exp per lane)
            int nidx = 0; float nw = 0.f;
            if (lane < dcount) {
                nidx = arow[lane];
                const float lgt = es1[nidx] + edv;
                nw = __expf(lgt > 0.f ? lgt : SLOPE * lgt);
            }
            float dsum = nw;
            #pragma unroll
            for (int m = 32; m > 0; m >>= 1) dsum += __shfl_xor(dsum, m, 64);
            const float inv = 1.f / (wself + dsum);

            a0 *= wself;
            a1 *= wself;

            int j = 0;
            for (; j + 2 <= dcount; j += 2) {
                const int   s0 = __shfl(nidx, j, 64);
                const int   s1 = __shfl(nidx, j + 1, 64);
                const float w0 = __shfl(nw, j, 64);
                const float w1 = __shfl(nw, j + 1, 64);
                const unsigned p0 = ((const unsigned*)(xp1 + (size_t)s0 * HD))[lane];
                const unsigned p1 = ((const unsigned*)(xp1 + (size_t)s1 * HD))[lane];
                a0 += w0 * bf2f(p0 & 0xFFFFu) + w1 * bf2f(p1 & 0xFFFFu);
                a1 += w0 * bf2f(p0 >> 16)     + w1 * bf2f(p1 >> 16);
            }
            if (j < dcount) {
                const int   s0 = __shfl(nidx, j, 64);
                const float w0 = __shfl(nw, j, 64);
                const unsigned p0 = ((const unsigned*)(xp1 + (size_t)s0 * HD))[lane];
                a0 += w0 * bf2f(p0 & 0xFFFFu);
                a1 += w0 * bf2f(p0 >> 16);
            }
            a0 *= inv;
            a1 *= inv;
        }
        // deg==0: denom == wself, numerator == wself * x  ->  a = x (already)

        const float o0 = fmaxf(a0 + b1a, 0.f);
        const float o1 = fmaxf(a1 + b1b, 0.f);

        float part = o0 * w2a + o1 * w2b;
        #pragma unroll
        for (int off = 32; off > 0; off >>= 1) part += __shfl_down(part, off, 64);
        if (lane == 0) {
            xp2[i] = part;
            if (dcount == 0) out[i] = part + b2v;   // layer-2 deg-0 finish
        }
    }
}

// ---------------------------------------------------------------------------
// K3: layer 2 over scalars — deg-0 nodes fully handled by k2 now, so ~67%
// of threads exit after one 4B deg read. Deg>0: round-5 exact body.
// ---------------------------------------------------------------------------
__global__ __launch_bounds__(256) void k3_final(
    const float* __restrict__ xp2, const int* __restrict__ deg,
    const int* __restrict__ adj,
    const float* __restrict__ a_src2, const float* __restrict__ a_dst2,
    const float* __restrict__ b2, float* __restrict__ out)
{
    const int i = blockIdx.x * 256 + threadIdx.x;
    if (i >= N_NODES) return;

    const int dcount = min(deg[i], CAP);
    if (dcount == 0) return;                 // out written by k2

    const float xi = xp2[i];
    const float as = a_src2[0], ad = a_dst2[0];
    const float adxi = ad * xi;
    const float s0 = (as + ad) * xi;
    const float l0 = s0 > 0.f ? s0 : SLOPE * s0;
    const float wself = __expf(l0);

    float denom = wself, num = wself * xi;
    const int* arow = adj + (size_t)i * CAP;

    int j = 0;
    for (; j + 2 <= dcount; j += 2) {
        const int2 ss = *(const int2*)(arow + j);
        const float x0 = xp2[ss.x];
        const float x1 = xp2[ss.y];
        float l0e = as * x0 + adxi; l0e = l0e > 0.f ? l0e : SLOPE * l0e;
        float l1e = as * x1 + adxi; l1e = l1e > 0.f ? l1e : SLOPE * l1e;
        const float w0 = __expf(l0e);
        const float w1 = __expf(l1e);
        denom += w0 + w1;
        num   += w0 * x0 + w1 * x1;
    }
    if (j < dcount) {
        const float x0 = xp2[arow[j]];
        float l0e = as * x0 + adxi; l0e = l0e > 0.f ? l0e : SLOPE * l0e;
        const float w0 = __expf(l0e);
        denom += w0;
        num   += w0 * x0;
    }
    out[i] = num / denom + b2[0];
}

extern "C" void kernel_launch(void* const* d_in, const int* in_sizes, int n_in,
                              void* d_out, int out_size, void* d_ws, size_t ws_size,
                              hipStream_t stream)
{
    const int* h   = (const int*)d_in[0];
    const int* ei  = (const int*)d_in[1];
    const int* nt  = (const int*)d_in[2];
    const float* emb    = (const float*)d_in[3];
    const float* W1     = (const float*)d_in[4];
    const float* a_src1 = (const float*)d_in[5];
    const float* a_dst1 = (const float*)d_in[6];
    const float* b1     = (const float*)d_in[7];
    const float* W2     = (const float*)d_in[8];
    const float* a_src2 = (const float*)d_in[9];
    const float* a_dst2 = (const float*)d_in[10];
    const float* b2     = (const float*)d_in[11];
    float* out = (float*)d_out;

    char* ws = (char*)d_ws;
    size_t off = 0;
    unsigned short* xp1 = (unsigned short*)(ws + off); off += (size_t)N_NODES * HD * sizeof(unsigned short);
    float* es1    = (float*)(ws + off); off += (size_t)N_NODES * sizeof(float);
    float* ed1    = (float*)(ws + off); off += (size_t)N_NODES * sizeof(float);
    float* denom1 = (float*)(ws + off); off += (size_t)N_NODES * sizeof(float);
    float* xp2    = (float*)(ws + off); off += (size_t)N_NODES * sizeof(float);
    int*   deg    = (int*)(ws + off);   off += (size_t)N_NODES * sizeof(int);
    unsigned* umask = (unsigned*)(ws + off); off += 3200 * sizeof(unsigned);
    unsigned short* W1bfT = (unsigned short*)(ws + off); off += (size_t)HD * HD * sizeof(unsigned short);
    off = (off + 255) & ~(size_t)255;
    int*   adj    = (int*)(ws + off);   off += (size_t)N_NODES * CAP * sizeof(int);

    k0_zero<<<NBLK, 256, 0, stream>>>(nt, W1, deg, umask, W1bfT);
    k1_fused<<<EB3 + GB, 512, 0, stream>>>(
        ei, umask, deg, adj,
        h, emb, W1bfT, a_src1, a_dst1, xp1, es1, ed1, denom1);
    k2_gather<<<K2B, 256, 0, stream>>>(
        xp1, denom1, es1, ed1, deg, adj, b1, W2, b2, xp2, out);
    k3_final<<<NBLK, 256, 0, stream>>>(
        xp2, deg, adj, a_src2, a_dst2, b2, out);
}

// Round 12
// 172.899 us; speedup vs baseline: 2.7295x; 1.0025x over previous
//
#include <hip/hip_runtime.h>

#define N_NODES 100000
#define N_EDGES 1600000
#define HD 128
#define SLOPE 0.2f
#define NBLK 391            // ceil(N_NODES/256)
#define GB 782              // gemm blocks: ceil(N_NODES/128)
#define EB4 782             // edge blocks: ceil(N_EDGES/4/512), 4 edges/thread
#define ETHREADS 400000     // N_EDGES / 4
#define CAP 32              // adjacency bucket capacity (P(deg>32) ~ 1e-19)
#define SLICE_LD 136        // padded LDS stage stride (shorts)
#define K2B 2048            // k2 persistent blocks (8192 waves grid-striding)

typedef __attribute__((ext_vector_type(8))) short bf16x8;
typedef __attribute__((ext_vector_type(4))) float f32x4;

__device__ __forceinline__ unsigned short f2bf(float f) {
    union { float f; unsigned u; } v; v.f = f;
    const unsigned u = v.u + 0x7FFFu + ((v.u >> 16) & 1u);   // RNE
    return (unsigned short)(u >> 16);
}
__device__ __forceinline__ unsigned pack2(float lo, float hi) {
    return (unsigned)f2bf(lo) | ((unsigned)f2bf(hi) << 16);
}
__device__ __forceinline__ float bf2f(unsigned u16) {
    union { unsigned u; float f; } v; v.u = u16 << 16; return v.f;
}

// ---------------------------------------------------------------------------
// K0: zero deg + node-active bitmask + W1^T bf16 convert. (round-5 exact)
// ---------------------------------------------------------------------------
__global__ __launch_bounds__(256) void k0_zero(
    const int* __restrict__ nt, const float* __restrict__ W1,
    int* __restrict__ deg, unsigned* __restrict__ umask,
    unsigned short* __restrict__ W1bfT)
{
    const int i = blockIdx.x * 256 + threadIdx.x;
    bool act = false;
    if (i < N_NODES) { deg[i] = 0; act = (nt[i] == 0); }
    const unsigned long long bal = __ballot(act);
    const int lane = threadIdx.x & 63;
    if (lane == 0)       umask[i >> 5] = (unsigned)bal;
    else if (lane == 32) umask[i >> 5] = (unsigned)(bal >> 32);
    if (i < HD * HD) {
        const int n = i >> 7, k = i & 127;
        W1bfT[n * HD + k] = f2bf(W1[k * HD + n]);
    }
}

// ---------------------------------------------------------------------------
// K1: FUSED edge bucket-build + gemm1 (round-11 structure, measured best).
// Change: edge path widened to 4 edges/thread via int4 loads — 782 edge
// blocks instead of 1563, halving edge-phase launch width; 2 independent
// int4 loads + 4 independent atomic chains per thread.
// Blocks [0,EB4): edges. Blocks [EB4, EB4+GB): gemm (round-11 body, exact).
// ---------------------------------------------------------------------------
__global__ __launch_bounds__(512, 8) void k1_fused(
    const int* __restrict__ ei,
    const unsigned* __restrict__ umask,
    int* __restrict__ deg,
    int* __restrict__ adj,
    const int* __restrict__ h,
    const float* __restrict__ emb,
    const unsigned short* __restrict__ W1bfT,
    const float* __restrict__ a_src1,
    const float* __restrict__ a_dst1,
    unsigned short* __restrict__ xp1,
    float* __restrict__ es1,
    float* __restrict__ ed1,
    float* __restrict__ denom1)
{
    __shared__ unsigned short Wlds[8 * 16 * SLICE_LD];   // 34 KB
    const int tid = threadIdx.x;

    if (blockIdx.x < EB4) {
        // ------------------------- edge path: 4 edges/thread --------------
        const int t = blockIdx.x * 512 + tid;
        if (t >= ETHREADS) return;
        const int e0 = t * 4;
        const int4 s4 = *(const int4*)(ei + e0);
        const int4 d4 = *(const int4*)(ei + N_EDGES + e0);

        const bool a0 =
            (((umask[s4.x >> 5] >> (s4.x & 31)) & (umask[d4.x >> 5] >> (d4.x & 31))) & 1u) != 0u;
        const bool a1 =
            (((umask[s4.y >> 5] >> (s4.y & 31)) & (umask[d4.y >> 5] >> (d4.y & 31))) & 1u) != 0u;
        const bool a2 =
            (((umask[s4.z >> 5] >> (s4.z & 31)) & (umask[d4.z >> 5] >> (d4.z & 31))) & 1u) != 0u;
        const bool a3 =
            (((umask[s4.w >> 5] >> (s4.w & 31)) & (umask[d4.w >> 5] >> (d4.w & 31))) & 1u) != 0u;

        if (a0) {
            const int sl = atomicAdd(deg + d4.x, 1);
            if (sl < CAP) adj[(size_t)d4.x * CAP + sl] = s4.x;
        }
        if (a1) {
            const int sl = atomicAdd(deg + d4.y, 1);
            if (sl < CAP) adj[(size_t)d4.y * CAP + sl] = s4.y;
        }
        if (a2) {
            const int sl = atomicAdd(deg + d4.z, 1);
            if (sl < CAP) adj[(size_t)d4.z * CAP + sl] = s4.z;
        }
        if (a3) {
            const int sl = atomicAdd(deg + d4.w, 1);
            if (sl < CAP) adj[(size_t)d4.w * CAP + sl] = s4.w;
        }
        return;
    }
    const int vb = blockIdx.x - EB4;           // gemm tile index 0..GB-1

    // ------------------------- gemm path (round-11 exact) -----------------
    // stage W^T: thread t -> col n = t>>2, k-quarter (t&3)*32, swizzled
    {
        const int n  = tid >> 2;
        const int kq = (tid & 3) * 32;
        const unsigned short* src = W1bfT + n * HD + kq;
        #pragma unroll
        for (int j = 0; j < 4; ++j) {
            const int c = (kq >> 3) + j;               // 16B chunk index along k
            const int p = c ^ (n & 7);                 // swizzle
            *(bf16x8*)(Wlds + n * HD + p * 8) = *(const bf16x8*)(src + j * 8);
        }
    }

    const int w   = tid >> 6;                          // 0..7
    const int L   = tid & 63;
    const int lm  = L & 15;
    const int lg  = L >> 4;
    const int wrow0 = vb * 128 + w * 16;

    const int arow = wrow0 + lm;
    const int g = (arow < N_NODES) ? arow : (N_NODES - 1);
    const float* xrow = emb + (size_t)h[g] * HD;

    __syncthreads();

    f32x4 acc[8];
    #pragma unroll
    for (int ct = 0; ct < 8; ++ct) acc[ct] = (f32x4)0.f;

    #pragma unroll
    for (int ks = 0; ks < 4; ++ks) {
        const int k0 = ks * 32 + lg * 8;
        const float4 u = *(const float4*)(xrow + k0);
        const float4 v = *(const float4*)(xrow + k0 + 4);
        union { bf16x8 b; unsigned x[4]; } t;
        t.x[0] = pack2(u.x, u.y);
        t.x[1] = pack2(u.z, u.w);
        t.x[2] = pack2(v.x, v.y);
        t.x[3] = pack2(v.z, v.w);
        const bf16x8 af = t.b;

        const int c = k0 >> 3;
        const int p = (c ^ (lm & 7)) * 8;              // n&7 == lm&7 for frag reads
        #pragma unroll
        for (int ct = 0; ct < 8; ++ct) {
            const bf16x8 bfr = *(const bf16x8*)(Wlds + (ct * 16 + lm) * HD + p);
            acc[ct] = __builtin_amdgcn_mfma_f32_16x16x32_bf16(af, bfr, acc[ct], 0, 0, 0);
        }
    }

    // attention dots (C/D: col = lm, row-in-tile = lg*4+reg)
    float asv[8], adv[8];
    #pragma unroll
    for (int ct = 0; ct < 8; ++ct) {
        asv[ct] = a_src1[ct * 16 + lm];
        adv[ct] = a_dst1[ct * 16 + lm];
    }

    #pragma unroll
    for (int reg = 0; reg < 4; ++reg) {
        const int row = wrow0 + lg * 4 + reg;
        float s = 0.f, d = 0.f;
        #pragma unroll
        for (int ct = 0; ct < 8; ++ct) {
            s += acc[ct][reg] * asv[ct];
            d += acc[ct][reg] * adv[ct];
        }
        #pragma unroll
        for (int m = 1; m < 16; m <<= 1) {   // reduce over the 16 lm lanes
            s += __shfl_xor(s, m, 64);
            d += __shfl_xor(d, m, 64);
        }
        if (row < N_NODES && lm == 0) {
            const float sum = s + d;
            const float l = sum > 0.f ? sum : SLOPE * sum;
            es1[row] = s;
            ed1[row] = d;
            denom1[row] = __expf(l);
        }
    }

    // ---- coalesced xp1 store via LDS transpose stage (W is dead) ----
    __syncthreads();                       // everyone done reading W from Wlds
    unsigned short* slice = Wlds + w * 16 * SLICE_LD;   // 16 rows, padded
    #pragma unroll
    for (int ct = 0; ct < 8; ++ct)
        #pragma unroll
        for (int reg = 0; reg < 4; ++reg)
            slice[(lg * 4 + reg) * SLICE_LD + ct * 16 + lm] = f2bf(acc[ct][reg]);
    __syncthreads();                       // order intra-wave LDS write->read
    #pragma unroll
    for (int rr = 0; rr < 4; ++rr) {
        const int rl = rr * 4 + lg;        // 0..15
        const int row = wrow0 + rl;
        if (row < N_NODES) {
            const bf16x8 vdat = *(const bf16x8*)(slice + rl * SLICE_LD + lm * 8);
            *(bf16x8*)(xp1 + (size_t)row * HD + lm * 8) = vdat;
        }
    }
}

// ---------------------------------------------------------------------------
// K2: gather layer 1, persistent 2048-block grid; deg-0 nodes also get their
// final layer-2 output here (out = xp2 + b2). (round-11 exact)
// ---------------------------------------------------------------------------
__global__ __launch_bounds__(256) void k2_gather(
    const unsigned short* __restrict__ xp1, const float* __restrict__ denom1,
    const float* __restrict__ es1, const float* __restrict__ ed1,
    const int* __restrict__ deg, const int* __restrict__ adj,
    const float* __restrict__ b1, const float* __restrict__ W2,
    const float* __restrict__ b2,
    float* __restrict__ xp2, float* __restrict__ out)
{
    const int wid = threadIdx.x >> 6;
    const int lane = threadIdx.x & 63;
    const float b1a = b1[2 * lane], b1b = b1[2 * lane + 1];
    const float w2a = W2[2 * lane], w2b = W2[2 * lane + 1];
    const float b2v = b2[0];

    for (int i = blockIdx.x * 4 + wid; i < N_NODES; i += K2B * 4) {
        const int dcount = min(deg[i], CAP);

        const unsigned pself = ((const unsigned*)(xp1 + (size_t)i * HD))[lane];
        float a0 = bf2f(pself & 0xFFFFu);
        float a1 = bf2f(pself >> 16);

        if (dcount > 0) {
            const float wself = denom1[i];
            const float edv   = ed1[i];
            const int* arow = adj + (size_t)i * CAP;

            // parallel neighbor metadata (one gather + exp per lane)
            int nidx = 0; float nw = 0.f;
            if (lane < dcount) {
                nidx = arow[lane];
                const float lgt = es1[nidx] + edv;
                nw = __expf(lgt > 0.f ? lgt : SLOPE * lgt);
            }
            float dsum = nw;
            #pragma unroll
            for (int m = 32; m > 0; m >>= 1) dsum += __shfl_xor(dsum, m, 64);
            const float inv = 1.f / (wself + dsum);

            a0 *= wself;
            a1 *= wself;

            int j = 0;
            for (; j + 2 <= dcount; j += 2) {
                const int   s0 = __shfl(nidx, j, 64);
                const int   s1 = __shfl(nidx, j + 1, 64);
                const float w0 = __shfl(nw, j, 64);
                const float w1 = __shfl(nw, j + 1, 64);
                const unsigned p0 = ((const unsigned*)(xp1 + (size_t)s0 * HD))[lane];
                const unsigned p1 = ((const unsigned*)(xp1 + (size_t)s1 * HD))[lane];
                a0 += w0 * bf2f(p0 & 0xFFFFu) + w1 * bf2f(p1 & 0xFFFFu);
                a1 += w0 * bf2f(p0 >> 16)     + w1 * bf2f(p1 >> 16);
            }
            if (j < dcount) {
                const int   s0 = __shfl(nidx, j, 64);
                const float w0 = __shfl(nw, j, 64);
                const unsigned p0 = ((const unsigned*)(xp1 + (size_t)s0 * HD))[lane];
                a0 += w0 * bf2f(p0 & 0xFFFFu);
                a1 += w0 * bf2f(p0 >> 16);
            }
            a0 *= inv;
            a1 *= inv;
        }
        // deg==0: denom == wself, numerator == wself * x  ->  a = x (already)

        const float o0 = fmaxf(a0 + b1a, 0.f);
        const float o1 = fmaxf(a1 + b1b, 0.f);

        float part = o0 * w2a + o1 * w2b;
        #pragma unroll
        for (int off = 32; off > 0; off >>= 1) part += __shfl_down(part, off, 64);
        if (lane == 0) {
            xp2[i] = part;
            if (dcount == 0) out[i] = part + b2v;   // layer-2 deg-0 finish
        }
    }
}

// ---------------------------------------------------------------------------
// K3: layer 2 over scalars — deg-0 handled by k2; deg>0: round-5 exact body.
// ---------------------------------------------------------------------------
__global__ __launch_bounds__(256) void k3_final(
    const float* __restrict__ xp2, const int* __restrict__ deg,
    const int* __restrict__ adj,
    const float* __restrict__ a_src2, const float* __restrict__ a_dst2,
    const float* __restrict__ b2, float* __restrict__ out)
{
    const int i = blockIdx.x * 256 + threadIdx.x;
    if (i >= N_NODES) return;

    const int dcount = min(deg[i], CAP);
    if (dcount == 0) return;                 // out written by k2

    const float xi = xp2[i];
    const float as = a_src2[0], ad = a_dst2[0];
    const float adxi = ad * xi;
    const float s0 = (as + ad) * xi;
    const float l0 = s0 > 0.f ? s0 : SLOPE * s0;
    const float wself = __expf(l0);

    float denom = wself, num = wself * xi;
    const int* arow = adj + (size_t)i * CAP;

    int j = 0;
    for (; j + 2 <= dcount; j += 2) {
        const int2 ss = *(const int2*)(arow + j);
        const float x0 = xp2[ss.x];
        const float x1 = xp2[ss.y];
        float l0e = as * x0 + adxi; l0e = l0e > 0.f ? l0e : SLOPE * l0e;
        float l1e = as * x1 + adxi; l1e = l1e > 0.f ? l1e : SLOPE * l1e;
        const float w0 = __expf(l0e);
        const float w1 = __expf(l1e);
        denom += w0 + w1;
        num   += w0 * x0 + w1 * x1;
    }
    if (j < dcount) {
        const float x0 = xp2[arow[j]];
        float l0e = as * x0 + adxi; l0e = l0e > 0.f ? l0e : SLOPE * l0e;
        const float w0 = __expf(l0e);
        denom += w0;
        num   += w0 * x0;
    }
    out[i] = num / denom + b2[0];
}

extern "C" void kernel_launch(void* const* d_in, const int* in_sizes, int n_in,
                              void* d_out, int out_size, void* d_ws, size_t ws_size,
                              hipStream_t stream)
{
    const int* h   = (const int*)d_in[0];
    const int* ei  = (const int*)d_in[1];
    const int* nt  = (const int*)d_in[2];
    const float* emb    = (const float*)d_in[3];
    const float* W1     = (const float*)d_in[4];
    const float* a_src1 = (const float*)d_in[5];
    const float* a_dst1 = (const float*)d_in[6];
    const float* b1     = (const float*)d_in[7];
    const float* W2     = (const float*)d_in[8];
    const float* a_src2 = (const float*)d_in[9];
    const float* a_dst2 = (const float*)d_in[10];
    const float* b2     = (const float*)d_in[11];
    float* out = (float*)d_out;

    char* ws = (char*)d_ws;
    size_t off = 0;
    unsigned short* xp1 = (unsigned short*)(ws + off); off += (size_t)N_NODES * HD * sizeof(unsigned short);
    float* es1    = (float*)(ws + off); off += (size_t)N_NODES * sizeof(float);
    float* ed1    = (float*)(ws + off); off += (size_t)N_NODES * sizeof(float);
    float* denom1 = (float*)(ws + off); off += (size_t)N_NODES * sizeof(float);
    float* xp2    = (float*)(ws + off); off += (size_t)N_NODES * sizeof(float);
    int*   deg    = (int*)(ws + off);   off += (size_t)N_NODES * sizeof(int);
    unsigned* umask = (unsigned*)(ws + off); off += 3200 * sizeof(unsigned);
    unsigned short* W1bfT = (unsigned short*)(ws + off); off += (size_t)HD * HD * sizeof(unsigned short);
    off = (off + 255) & ~(size_t)255;
    int*   adj    = (int*)(ws + off);   off += (size_t)N_NODES * CAP * sizeof(int);

    k0_zero<<<NBLK, 256, 0, stream>>>(nt, W1, deg, umask, W1bfT);
    k1_fused<<<EB4 + GB, 512, 0, stream>>>(
        ei, umask, deg, adj,
        h, emb, W1bfT, a_src1, a_dst1, xp1, es1, ed1, denom1);
    k2_gather<<<K2B, 256, 0, stream>>>(
        xp1, denom1, es1, ed1, deg, adj, b1, W2, b2, xp2, out);
    k3_final<<<NBLK, 256, 0, stream>>>(
        xp2, deg, adj, a_src2, a_dst2, b2, out);
}